// Round 16
// baseline (560.735 us; speedup 1.0000x reference)
//
#include <hip/hip_runtime.h>
#include <cstdint>
#include <cstddef>

#define Hn 8192
#define Nn 4096
#define Cn 128
#define Tt 256
#define CAP 192

typedef unsigned long long ull;

// th after nup clip-updates (decay -0.05 each) from base b, clamped [lo,hi]
__device__ __forceinline__ float th_lazy2(float b, float lo, float hi, int nup){
    if (nup <= 0) return b;
    float a = fminf(fmaxf(__fsub_rn(b, 0.05f), lo), hi);
    if (nup == 1) return a;
    return fmaxf(__fsub_rn(a, __fmul_rn(0.05f, (float)(nup - 1))), lo);
}

__device__ __forceinline__ float clamp01(float v){
    return fminf(fmaxf(v, 0.f), 1.f);
}

// ---- DPP cross-lane reduce (VALU pipe) ----
template<int CTRL>
__device__ __forceinline__ int dpp_i(int x, int old){
    return __builtin_amdgcn_update_dpp(old, x, CTRL, 0xf, 0xf, false);
}
__device__ __forceinline__ float wave_max_f(float v){
    const int NEG = __float_as_int(-3.4e38f);
#define STEPM(C) { float o = __int_as_float(dpp_i<C>(__float_as_int(v), NEG)); v = fmaxf(v, o); }
    STEPM(0x111) STEPM(0x112) STEPM(0x114) STEPM(0x118) STEPM(0x142) STEPM(0x143)
#undef STEPM
    return __int_as_float(__builtin_amdgcn_readlane(__float_as_int(v), 63));
}
// argmax (value desc, index asc); returns winner lane, sets wv/wh.
__device__ __forceinline__ int wave_argmax_l(float bv, int bh, float &wv, int &wh){
    float v = wave_max_f(bv);
    ull tie = __ballot(bv == v);
    int tl = __ffsll((long long)tie) - 1;
    int h = __builtin_amdgcn_readlane(bh, tl);
    if (__builtin_expect(__popcll(tie) > 1, 0)){
        ull m = tie & (tie - 1);
        while (m){
            int l2 = __ffsll((long long)m) - 1;
            int h2 = __builtin_amdgcn_readlane(bh, l2);
            if (h2 < h){ h = h2; tl = l2; }
            m &= m - 1;
        }
    }
    wv = v; wh = h; return tl;
}
__device__ __forceinline__ float rl_f(float x, int l){
    return __int_as_float(__builtin_amdgcn_readlane(__float_as_int(x), l));
}

// ---------------- k_prep: buckets + counting sort + image exp tables ----------------
__global__ __launch_bounds__(1024) void k_prep(const float* __restrict__ image,
        int* __restrict__ boff, int* __restrict__ sidx, unsigned* __restrict__ anyv,
        float* __restrict__ imgt, float* __restrict__ eiP, float* __restrict__ eiM){
    __shared__ int s_start[Nn];
    __shared__ int s_c4[4][Tt];
    __shared__ int s_boff[Tt + 1];
    int tid = threadIdx.x;
    for (int i = tid; i < Nn; i += 1024){
        float im = image[i];
        float img = __fmul_rn(256.f, im);
        s_start[i] = (int)floorf(img);
        imgt[i] = img;
        eiP[i] = __expf(img * 0.05f);
        eiM[i] = __expf(-img * 0.05f);
    }
    if (tid < Tt) anyv[tid] = 0u;
    __syncthreads();
    int b = tid & 255, q = tid >> 8;
    {
        int c = 0;
        for (int k = 0; k < 1024; ++k) c += (s_start[q * 1024 + k] == b) ? 1 : 0;
        s_c4[q][b] = c;
    }
    __syncthreads();
    if (tid == 0){
        int acc = 0;
        for (int bb = 0; bb < Tt; ++bb){
            s_boff[bb] = acc;
            acc += s_c4[0][bb] + s_c4[1][bb] + s_c4[2][bb] + s_c4[3][bb];
        }
        s_boff[Tt] = acc;
    }
    __syncthreads();
    if (tid <= Tt) boff[tid] = s_boff[tid];
    int p = s_boff[b];
    if (q > 0) p += s_c4[0][b];
    if (q > 1) p += s_c4[1][b];
    if (q > 2) p += s_c4[2][b];
    for (int k = 0; k < 1024; ++k){
        int i = q * 1024 + k;
        if (s_start[i] == b) sidx[p++] = i;
    }
}

// ---------------- k_gbuckets: 2 rows/block, 32 KB LDS ----------------
__global__ __launch_bounds__(256) void k_gbuckets(const float* __restrict__ W1,
        const int* __restrict__ boff, const int* __restrict__ sidx,
        float* __restrict__ G_T){
    __shared__ float rows[2][Nn];
    int tid = threadIdx.x;
    int h0 = blockIdx.x * 2;
    for (int r = 0; r < 2; ++r){
        const float4* src = (const float4*)(W1 + (size_t)(h0 + r) * Nn);
        float4* dst = (float4*)rows[r];
        for (int j = tid; j < Nn / 4; j += 256) dst[j] = src[j];
    }
    __syncthreads();
    int t = tid;
    int b0 = boff[t], b1 = boff[t + 1];
    float s0 = 0.f, s1 = 0.f;
    for (int k = b0; k < b1; ++k){
        int i = sidx[k];
        s0 += rows[0][i]; s1 += rows[1][i];
    }
    G_T[(size_t)(h0 + 0) * Tt + t] = s0;
    G_T[(size_t)(h0 + 1) * Tt + t] = s1;
}

// ---------------- k_w1bulk: o_W1 = W1 + 0.01 (W1 L3-resident; full occupancy) ----------------
__global__ __launch_bounds__(256) void k_w1bulk(const float* __restrict__ W1,
        float* __restrict__ o_W1){
    size_t base = (size_t)blockIdx.x * 4096;
    const float4* src = (const float4*)W1;
    float4* dst = (float4*)o_W1;
    for (int i = threadIdx.x; i < 4096; i += 256){
        float4 s = src[base + i];
        s.x = __fadd_rn(s.x, 0.01f); s.y = __fadd_rn(s.y, 0.01f);
        s.z = __fadd_rn(s.z, 0.01f); s.w = __fadd_rn(s.w, 0.01f);
        dst[base + i] = s;
    }
}

// ---------------- k_c1M: window-sum + M-scan + r1 init ----------------
__global__ __launch_bounds__(256) void k_c1M(const float* __restrict__ G_T,
        float* __restrict__ M, float* __restrict__ r1pre, float* __restrict__ o_r1){
    __shared__ float tile[32][Tt + 1];
    __shared__ float c1s[32][Tt + 1];
    const int tid = threadIdx.x;
    const int h0 = blockIdx.x * 32;
    for (int r = 0; r < 32; ++r) tile[r][tid] = G_T[(size_t)(h0 + r) * Tt + tid];
    __syncthreads();
    {
        int hs = tid & 31, ts = tid >> 5;
        for (int tb = 0; tb < 32; ++tb){
            int t = tb * 8 + ts;
            int lo = (t - 7 < 0) ? 0 : t - 7;
            float s = 0.f;
            for (int u = lo; u <= t; ++u) s += tile[hs][u];
            c1s[hs][t] = s;
        }
    }
    __syncthreads();
    if (tid < 32){
        float m = 0.f;
        for (int t = 0; t < Tt; ++t){
            m = __fadd_rn(__fmul_rn(0.9f, m), c1s[tid][t]);
            M[(size_t)t * Hn + h0 + tid] = m;
        }
        r1pre[h0 + tid] = 0.f;
        o_r1[h0 + tid] = 256.f;
    }
}

// ---------------- k_sel: rank-CAP radix select; cand = (val, idx|valid<<15, 0, vcap) ----------------
__global__ __launch_bounds__(256) void k_sel(const float* __restrict__ M,
        float4* __restrict__ cand){
    const int t = blockIdx.x, tid = threadIdx.x;
    __shared__ float s_row[Hn];
    __shared__ unsigned s_hist[256];
    __shared__ unsigned s_suf[256];
    __shared__ unsigned s_pref;
    __shared__ int s_rank;
    __shared__ int s_cnt;
    __shared__ int s_idx[CAP + 64];
    {
        const float4* src = (const float4*)(M + (size_t)t * Hn);
        float4* d4 = (float4*)s_row;
        for (int j = tid; j < Hn / 4; j += 256) d4[j] = src[j];
    }
    if (tid == 0){ s_pref = 0u; s_rank = CAP; s_cnt = 0; }
    __syncthreads();
#pragma unroll
    for (int b = 3; b >= 0; --b){
        s_hist[tid] = 0u;
        __syncthreads();
        unsigned pref = s_pref;
        int r = s_rank;
        for (int k = 0; k < 32; ++k){
            unsigned u = __float_as_uint(s_row[tid + (k << 8)]);
            bool match = (b == 3) ? true : ((u >> ((b + 1) * 8)) == pref);
            if (match) atomicAdd(&s_hist[(u >> (b * 8)) & 255], 1u);
        }
        __syncthreads();
        s_suf[tid] = s_hist[tid];
        __syncthreads();
#pragma unroll
        for (int off = 1; off < 256; off <<= 1){
            unsigned v = (tid + off < 256) ? s_suf[tid + off] : 0u;
            __syncthreads();
            s_suf[tid] += v;
            __syncthreads();
        }
        unsigned above = s_suf[tid] - s_hist[tid];
        if ((int)above < r && r <= (int)s_suf[tid]){
            s_pref = (pref << 8) | (unsigned)tid;
            s_rank = r - (int)above;
        }
        __syncthreads();
    }
    unsigned V = s_pref;
    for (int k = 0; k < 32; ++k){
        int i = tid + (k << 8);
        unsigned u = __float_as_uint(s_row[i]);
        if (u >= V){
            int p = atomicAdd(&s_cnt, 1);
            if (p < CAP + 64) s_idx[p] = i;
        }
    }
    __syncthreads();
    int c = s_cnt;
    bool ovf = (c > CAP);
    float vV = ovf ? 3.4e38f : __uint_as_float(V);
    for (int i = tid; i < CAP; i += 256){
        float4 e;
        if (!ovf && i < c){
            int ix = s_idx[i];
            e = make_float4(s_row[ix], __int_as_float(ix | (1 << 15)), 0.f, vV);
        } else {
            e = make_float4(-1.f, 0.f, 0.f, vV);
        }
        cand[(size_t)t * CAP + i] = e;
    }
}

// ---------------- k_fused: block0 = r10-style WTA + postmap; blocks 1.. = W2 bulk + W3T ----------------
#define NB_W2 2048
#define NB_W3T 128

union FusedLDS {
    struct {
        float4 mst[Hn];             // 128 KB (off, ts, thb, 0)
        int j1[Tt];                 // 1 KB
        unsigned bm[256];           // 1 KB
    } w;
    float tl[64][65];               // W3T tile
};

__global__ __launch_bounds__(512, 1) void k_fused(
        const float* __restrict__ M, const float4* __restrict__ cand,
        const float* __restrict__ thr1,
        const float* __restrict__ W2, const float* __restrict__ W3,
        float* __restrict__ o_W2, float* __restrict__ W3T,
        float* __restrict__ r1pre, float* __restrict__ o_r1,
        int* __restrict__ j1s, int* __restrict__ mh, int* __restrict__ nRout){
    __shared__ FusedLDS u;
    const int bid = blockIdx.x;
    const int tid = threadIdx.x;

    if (bid >= 1 && bid < 1 + NB_W2){
        size_t base = (size_t)(bid - 1) * 4096;
        const float4* src = (const float4*)W2;
        float4* dst = (float4*)o_W2;
        for (int i = tid; i < 4096; i += 2048){
            float4 a0 = src[base + i];
            float4 a1 = src[base + i + 512];
            float4 a2 = src[base + i + 1024];
            float4 a3 = src[base + i + 1536];
            a0.x = clamp01(a0.x); a0.y = clamp01(a0.y); a0.z = clamp01(a0.z); a0.w = clamp01(a0.w);
            a1.x = clamp01(a1.x); a1.y = clamp01(a1.y); a1.z = clamp01(a1.z); a1.w = clamp01(a1.w);
            a2.x = clamp01(a2.x); a2.y = clamp01(a2.y); a2.z = clamp01(a2.z); a2.w = clamp01(a2.w);
            a3.x = clamp01(a3.x); a3.y = clamp01(a3.y); a3.z = clamp01(a3.z); a3.w = clamp01(a3.w);
            dst[base + i]        = a0;
            dst[base + i + 512]  = a1;
            dst[base + i + 1024] = a2;
            dst[base + i + 1536] = a3;
        }
        return;
    }
    if (bid >= 1 + NB_W2){
        int r = bid - 1 - NB_W2;
        int bx = r & 63, by = r >> 6;
        int n0 = bx * 64, c0 = by * 64;
        for (int e = tid; e < 64 * 64; e += 512){
            int rr = e >> 6, cc = e & 63;
            u.tl[rr][cc] = W3[(size_t)(c0 + rr) * Nn + n0 + cc];
        }
        __syncthreads();
        for (int e = tid; e < 64 * 64; e += 512){
            int rn = e >> 6, cc = e & 63;
            W3T[(size_t)(n0 + rn) * Cn + c0 + cc] = u.tl[cc][rn];
        }
        return;
    }

    // ---- block 0: init state table, then single-wave WTA ----
    for (int h = tid; h < Hn; h += 512)
        u.w.mst[h] = make_float4(0.f, -1.f, thr1[h], 0.f);
    __syncthreads();
    if (tid >= 64) return;
    const int lane = tid;
    const float Lc = -0.15200309344504997f;   // log2(0.9)

    float4 cA0 = cand[lane],         cA1 = cand[64 + lane],         cA2 = cand[128 + lane];
    float4 cB0 = cand[CAP + lane],   cB1 = cand[CAP + 64 + lane],   cB2 = cand[CAP + 128 + lane];
    float4 cC0 = cand[2*CAP + lane], cC1 = cand[2*CAP + 64 + lane], cC2 = cand[2*CAP + 128 + lane];
    float4 gA0, gA1, gA2;
    {
        int h0 = __float_as_int(cA0.y) & 8191;
        int h1 = __float_as_int(cA1.y) & 8191;
        int h2 = __float_as_int(cA2.y) & 8191;
        gA0 = u.w.mst[h0]; gA1 = u.w.mst[h1]; gA2 = u.w.mst[h2];
    }

    for (int t = 0; t < Tt; ++t){
        const float tf = (float)t;
        float bm = -3.4e38f; int bhh = 0x7FFFFFFF;
        float braw = 0.f, bts = 0.f, bthb = 0.f;
#define CPROC(c) { \
        int mc = __float_as_int(cA##c.y); \
        int hc = mc & 8191; \
        float dd = __fsub_rn(tf, gA##c.y); \
        float mem = __fsub_rn(cA##c.x, __fmul_rn(exp2f(__fmul_rn(dd, Lc)), gA##c.x)); \
        if (!((mc >> 15) & 1)) mem = -3.4e38f; \
        if (mem > bm || (mem == bm && hc < bhh)){ bm = mem; bhh = hc; braw = cA##c.x; bts = gA##c.y; bthb = gA##c.z; } }
        CPROC(0) CPROC(1) CPROC(2)
#undef CPROC
        const int hB0 = __float_as_int(cB0.y) & 8191;
        const int hB1 = __float_as_int(cB1.y) & 8191;
        const int hB2 = __float_as_int(cB2.y) & 8191;
        float4 gB0 = u.w.mst[hB0];
        float4 gB1 = u.w.mst[hB1];
        float4 gB2 = u.w.mst[hB2];
        float wv; int wh;
        int wl = wave_argmax_l(bm, bhh, wv, wh);
        float raw = rl_f(braw, wl), tsv = rl_f(bts, wl), thb = rl_f(bthb, wl);
        const float vc = cA0.w;
        int skip = 0;
        if (__builtin_expect(wv < vc, 0)){
            if (t > 0 && vc < 150.f){
                skip = 1;
            } else {
                float fv = -3.4e38f; int fh = 0x7FFFFFFF;
                float fraw = 0.f, fts = 0.f, fthb = 0.f;
                const float4* Mrow4 = (const float4*)(M + (size_t)t * Hn);
                for (int q = 0; q < 32; ++q){
                    int e = q * 64 + lane;
                    float4 mv = Mrow4[e];
                    int ib = e * 4;
                    float4 g0 = u.w.mst[ib+0], g1 = u.w.mst[ib+1], g2 = u.w.mst[ib+2], g3 = u.w.mst[ib+3];
#define FPROC(comp, gg, o2) { float x = mv.comp; float dd = __fsub_rn(tf, gg.y); \
                    float mm = __fsub_rn(x, __fmul_rn(exp2f(__fmul_rn(dd, Lc)), gg.x)); \
                    int h2 = ib + o2; \
                    if (mm > fv || (mm == fv && h2 < fh)){ fv = mm; fh = h2; fraw = x; fts = gg.y; fthb = gg.z; } }
                    FPROC(x, g0, 0) FPROC(y, g1, 1) FPROC(z, g2, 2) FPROC(w, g3, 3)
#undef FPROC
                }
                wl = wave_argmax_l(fv, fh, wv, wh);
                raw = rl_f(fraw, wl); tsv = rl_f(fts, wl); thb = rl_f(fthb, wl);
            }
        }
        int fire = 0; float thnew = 0.f;
        if (!skip){
            float te = th_lazy2(thb, 150.f, 400.f, t - (int)tsv - 1);
            if (wv > te){
                fire = 1;
                thnew = fminf(fmaxf(__fadd_rn(__fsub_rn(te, 0.05f), 5.0f), 150.f), 400.f);
            }
        }
        if (fire){
            if (lane == 0){
                u.w.j1[t] = wh;
                if (tsv < 0.f){ o_r1[wh] = tf + 1.f; r1pre[wh] = tf + 1.f; }
                u.w.mst[wh] = make_float4(raw, tf, thnew, 0.f);
            }
            float4 upd = make_float4(raw, tf, thnew, 0.f);
            if (hB0 == wh) gB0 = upd;
            if (hB1 == wh) gB1 = upd;
            if (hB2 == wh) gB2 = upd;
        } else {
            if (lane == 0) u.w.j1[t] = -1;
        }
        cA0 = cB0; cA1 = cB1; cA2 = cB2;
        cB0 = cC0; cB1 = cC1; cB2 = cC2;
        int tn = (t + 3 < Tt) ? t + 3 : Tt - 1;
        cC0 = cand[(size_t)tn * CAP + lane];
        cC1 = cand[(size_t)tn * CAP + 64 + lane];
        cC2 = cand[(size_t)tn * CAP + 128 + lane];
        gA0 = gB0; gA1 = gB1; gA2 = gB2;
    }

    // ---- single-wave postmap ----
    for (int i = lane; i < 256; i += 64) u.w.bm[i] = 0u;
    asm volatile("s_waitcnt lgkmcnt(0)" ::: "memory");
    for (int i = lane; i < Tt; i += 64){
        int h = u.w.j1[i];
        j1s[i] = h;
        if (h >= 0) atomicOr(&u.w.bm[h >> 5], 1u << (h & 31));
    }
    asm volatile("s_waitcnt lgkmcnt(0)" ::: "memory");
    unsigned w0 = u.w.bm[lane*4+0], w1 = u.w.bm[lane*4+1];
    unsigned w2 = u.w.bm[lane*4+2], w3 = u.w.bm[lane*4+3];
    int c = __popc(w0) + __popc(w1) + __popc(w2) + __popc(w3);
    int inc = c;
#pragma unroll
    for (int off = 1; off < 64; off <<= 1){
        int v = __shfl_up(inc, off);
        if (lane >= off) inc += v;
    }
    int b = inc - c;
#define WALK(wrd, k) { unsigned ww = wrd; while (ww){ int bt = __ffs(ww) - 1; ww &= ww - 1; \
        mh[b++] = ((lane * 4 + k) << 5) | bt; } }
    WALK(w0, 0) WALK(w1, 1) WALK(w2, 2) WALK(w3, 3)
#undef WALK
    if (lane == 63) *nRout = inc;
}

// ---------------- k_lif2: direct-W2 LIF, depth-4 named-reg prefetch ----------------
__global__ __launch_bounds__(64) void k_lif2(const float* __restrict__ W2,
        const int* __restrict__ j1s, const float* __restrict__ thr2,
        float* __restrict__ o_r2, ull* __restrict__ spkb, unsigned* __restrict__ anyv){
    __shared__ int s_j[Tt];
    int lane = threadIdx.x, blk = blockIdx.x;
    for (int i = lane; i < Tt; i += 64) s_j[i] = j1s[i];
    __syncthreads();
    int n = blk * 64 + lane;
    const float* Wrow = W2 + (size_t)n * Hn;
    float tv = thr2[n], m = 0.f, rp = 0.f;
#define LD(dst, tt) { int hh = s_j[tt]; dst = (hh >= 0) ? Wrow[hh] : 0.f; }
#define STEP(uu, tt) { m = __fadd_rn(__fmul_rn(0.8f, m), uu); int f = 0; \
        if (m > tv){ m = __fsub_rn(m, tv); if (rp == 0.f) rp = (float)((tt) + 1); f = 1; } \
        ull mask = __ballot(f); \
        if (lane == 0){ spkb[(tt) * 64 + blk] = mask; if (mask) atomicOr(&anyv[tt], 1u); } }
    float u0, u1, u2, u3;
    LD(u0, 0) LD(u1, 1) LD(u2, 2) LD(u3, 3)
    for (int g = 0; g < 64; ++g){
        float v0 = 0.f, v1 = 0.f, v2 = 0.f, v3 = 0.f;
        if (g < 63){
            int bb = (g + 1) * 4;
            LD(v0, bb) LD(v1, bb + 1) LD(v2, bb + 2) LD(v3, bb + 3)
        }
        int t = g * 4;
        STEP(u0, t) STEP(u1, t + 1) STEP(u2, t + 2) STEP(u3, t + 3)
        u0 = v0; u1 = v1; u2 = v2; u3 = v3;
    }
#undef LD
#undef STEP
    o_r2[n] = (rp == 0.f) ? 256.f : rp;
}

// ---------------- k_sim3: spkb preloaded to LDS (128 KB) ----------------
__global__ __launch_bounds__(128, 1) void k_sim3(const ull* __restrict__ spkb,
        const unsigned* __restrict__ anyv, const float* __restrict__ W3T,
        const float* __restrict__ thr3, float* __restrict__ o_r3){
    int tid = threadIdx.x, lane = tid & 63, w = tid >> 6;
    __shared__ ull s_spk[Tt * 64];     // 128 KB
    __shared__ unsigned s_any[Tt];
    __shared__ ull s_r2[2];
    __shared__ int s_fire;
    {
        const uint4* src = (const uint4*)spkb;
        uint4* dst = (uint4*)s_spk;
        for (int i = tid; i < Tt * 64 / 2; i += 128) dst[i] = src[i];
    }
    for (int i = tid; i < Tt; i += 128) s_any[i] = anyv[i];
    float m = 0.f, th0 = thr3[tid], rp = 0.f, thv = 0.f;
    int ts = -1, zero = 1;
    __syncthreads();
    for (int t = 0; t < Tt; ++t){
        if (zero && s_any[t] == 0u) continue;
        float d = 0.f;
        if (s_any[t]){
            for (int ww = 0; ww < 64; ++ww){
                ull bits = s_spk[t * 64 + ww];
                while (bits){
                    int b2 = __ffsll((long long)bits) - 1;
                    bits &= bits - 1;
                    d = __fadd_rn(d, W3T[(size_t)(ww * 64 + b2) * Cn + tid]);
                }
            }
        }
        m = __fadd_rn(__fmul_rn(0.9f, m), d);
        ull k = (((ull)__float_as_uint(m >= 0.f ? m : 0.f)) << 32) | (unsigned)(8191 - tid);
        if (!(m >= 0.f)) k = (unsigned)(8191 - tid);
#pragma unroll
        for (int off = 32; off >= 1; off >>= 1){
            ull o = __shfl_down(k, off);
            if (o > k) k = o;
        }
        if (lane == 0) s_r2[w] = k;
        __syncthreads();
        ull wk = s_r2[0] > s_r2[1] ? s_r2[0] : s_r2[1];
        int wc = 8191 - (int)(wk & 0xFFFFu);
        float wv = __uint_as_float((unsigned)(wk >> 32));
        if (tid == wc){
            float te = (ts < 0) ? th_lazy2(th0, 50.f, 200.f, t)
                                : th_lazy2(thv, 50.f, 200.f, t - ts - 1);
            int f = (wv > te) ? 1 : 0;
            s_fire = f;
            if (f){
                thv = fminf(fmaxf(__fadd_rn(__fsub_rn(te, 0.05f), 5.0f), 50.f), 200.f);
                ts = t;
                if (rp == 0.f) rp = (float)(t + 1);
            }
        }
        __syncthreads();
        if (s_fire){ m = 0.f; zero = 1; }
        else zero = 0;
        __syncthreads();
    }
    o_r3[tid] = (rp == 0.f) ? 256.f : rp;
}

// ---------------- k_post: block0 = scalars; 1..256 = w1fix; 257..384 = w3new ----------------
__global__ __launch_bounds__(256) void k_post(const float* __restrict__ image,
        const float* __restrict__ r1pre, const float* __restrict__ o_r1,
        const float* __restrict__ o_r2, const float* __restrict__ o_r3,
        const float* __restrict__ imgt, const float* __restrict__ eiP,
        const float* __restrict__ eiM,
        const float* __restrict__ W1, const float* __restrict__ W3,
        const int* __restrict__ mh, const int* __restrict__ nRout,
        float* __restrict__ zeta, float* __restrict__ rho,
        float* __restrict__ Pv, float* __restrict__ Qv,
        float* __restrict__ o_err, float* __restrict__ o_es,
        float* __restrict__ o_W1, float* __restrict__ o_W3){
    const int bid = blockIdx.x;
    const int tid = threadIdx.x;
    if (bid == 0){
        // scalars
        for (int h = tid; h < Hn; h += 256){
            float r1f = o_r1[h];
            float mask = (r1pre[h] != 0.f) ? 1.f : 0.f;
            float z = __fmul_rn(__fmul_rn(__fsub_rn(256.f, r1f), mask), 0.00390625f);
            zeta[h] = z;
            Pv[h] = __expf(r1f * 0.05f) * z;
            Qv[h] = __expf(-r1f * 0.05f) * z;
        }
        float acc = 0.f;
        for (int n = tid; n < Nn; n += 256){
            float img = __fmul_rn(256.f, image[n]);
            float r2f = o_r2[n];
            float e = __fmul_rn(__fsub_rn(img, __fsub_rn(r2f, 4.0f)), 0.00390625f);
            o_err[n] = e;
            rho[n] = __fadd_rn(__fmul_rn(__fsub_rn(__fsub_rn(r2f, 4.0f), img), 0.00390625f), 0.15f);
            acc = __fadd_rn(acc, __fmul_rn(e, e));
        }
        __shared__ float red[4];
        for (int off = 32; off >= 1; off >>= 1) acc += __shfl_down(acc, off);
        int lane = tid & 63, w = tid >> 6;
        if (lane == 0) red[w] = acc;
        __syncthreads();
        if (tid == 0) *o_es = red[0] + red[1] + red[2] + red[3];
        return;
    }
    if (bid <= 256){
        // w1fix
        int slot = bid - 1;
        if (slot >= *nRout) return;
        int h = mh[slot];
        float r1f = o_r1[h];
        float a = 0.01f * __expf(-r1f * 0.05f);
        float b = 0.01f * __expf( r1f * 0.05f);
        const float4* src = (const float4*)(W1 + (size_t)h * Nn);
        float4* dst = (float4*)(o_W1 + (size_t)h * Nn);
        const float4* ig = (const float4*)imgt;
        const float4* p4 = (const float4*)eiP;
        const float4* m4 = (const float4*)eiM;
        for (int i = tid; i < Nn / 4; i += 256){
            float4 s = src[i];
            float4 im = ig[i], pp = p4[i], mm = m4[i];
            s.x += (r1f >= im.x) ? a * pp.x : -(b * mm.x);
            s.y += (r1f >= im.y) ? a * pp.y : -(b * mm.y);
            s.z += (r1f >= im.z) ? a * pp.z : -(b * mm.z);
            s.w += (r1f >= im.w) ? a * pp.w : -(b * mm.w);
            dst[i] = s;
        }
        return;
    }
    {
        // w3new (inline exp over r2 — W3 is tiny)
        int cc = bid - 257;
        float r3f = o_r3[cc];
        float a = 0.01f * __expf(-r3f * 0.05f);
        float b = 0.01f * __expf( r3f * 0.05f);
        const float4* src = (const float4*)(W3 + (size_t)cc * Nn);
        float4* dst = (float4*)(o_W3 + (size_t)cc * Nn);
        const float4* r24 = (const float4*)o_r2;
        for (int i = tid; i < Nn / 4; i += 256){
            float4 s = src[i]; float4 rv = r24[i];
            s.x += (r3f >= rv.x) ? a * __expf(rv.x * 0.05f) : -(b * __expf(-rv.x * 0.05f));
            s.y += (r3f >= rv.y) ? a * __expf(rv.y * 0.05f) : -(b * __expf(-rv.y * 0.05f));
            s.z += (r3f >= rv.z) ? a * __expf(rv.z * 0.05f) : -(b * __expf(-rv.z * 0.05f));
            s.w += (r3f >= rv.w) ? a * __expf(rv.w * 0.05f) : -(b * __expf(-rv.w * 0.05f));
            dst[i] = s;
        }
    }
}

// ---------------- k_w2fix ----------------
__global__ __launch_bounds__(128) void k_w2fix(
        const float* __restrict__ o_r1, const float* __restrict__ Pv,
        const float* __restrict__ Qv, const float* __restrict__ o_r2,
        const float* __restrict__ rho, const int* __restrict__ mh,
        const int* __restrict__ nRout, float* __restrict__ o_W2){
    __shared__ int   s_h[Tt];
    __shared__ float s_rv[Tt], s_pp[Tt], s_qq[Tt];
    int n = blockIdx.x, tid = threadIdx.x;
    int nRv = *nRout;
    for (int s = tid; s < nRv; s += 128){
        int h = mh[s];
        s_h[s] = h; s_rv[s] = o_r1[h]; s_pp[s] = Pv[h]; s_qq[s] = Qv[h];
    }
    __syncthreads();
    float r2f = o_r2[n], rh = rho[n];
    float A = 0.01f * rh * __expf(-r2f * 0.05f);
    float B = 0.01f * rh * __expf( r2f * 0.05f);
    for (int s = tid; s < nRv; s += 128){
        size_t idx = (size_t)n * Hn + s_h[s];
        float w = o_W2[idx];
        float rv = s_rv[s];
        w = clamp01(w + ((r2f >= rv) ? A * s_pp[s] : -(B * s_qq[s])));
        o_W2[idx] = w;
    }
}

extern "C" void kernel_launch(void* const* d_in, const int* in_sizes, int n_in,
                              void* d_out, int out_size, void* d_ws, size_t ws_size,
                              hipStream_t stream){
    const float* image = (const float*)d_in[0];
    const float* W1   = (const float*)d_in[1];
    const float* W2   = (const float*)d_in[2];
    const float* W3   = (const float*)d_in[3];
    const float* thr1 = (const float*)d_in[4];
    const float* thr2 = (const float*)d_in[5];
    const float* thr3 = (const float*)d_in[6];

    float* out  = (float*)d_out;
    float* o_err = out;
    float* o_es  = out + 4096;
    float* o_r1  = out + 4097;
    float* o_r2  = out + 12289;
    float* o_r3  = out + 16385;
    float* o_W1  = out + 16513;
    float* o_W2  = o_W1 + (size_t)Hn * Nn;
    float* o_W3  = o_W2 + (size_t)Nn * Hn;

    float* ws = (float*)d_ws;
    float* G_T   = ws;                                  // H*T
    float* M     = G_T + (size_t)Hn * Tt;               // T*H
    float* W3T   = M + (size_t)Tt * Hn;                 // N*C
    float4* cand = (float4*)(W3T + (size_t)Nn * Cn);    // T*CAP float4
    ull* spkb    = (ull*)(cand + (size_t)Tt * CAP);     // T*64
    float* r1pre = (float*)(spkb + (size_t)Tt * 64);    // H
    float* zeta  = r1pre + Hn;                          // H
    float* rho   = zeta + Hn;                           // N
    float* imgt  = rho + Nn;                            // N
    float* eiP   = imgt + Nn;                           // N
    float* eiM   = eiP + Nn;                            // N
    float* Pv    = eiM + Nn;                            // H
    float* Qv    = Pv + Hn;                             // H
    int* boff   = (int*)(Qv + Hn);                      // T+1
    int* sidx   = boff + (Tt + 1);                      // N
    int* j1s    = sidx + Nn;                            // T (h-indices)
    int* mh     = j1s + Tt;                             // 256
    int* nRout  = mh + 256;                             // 1
    unsigned* anyv = (unsigned*)(nRout + 1);            // T

    k_prep<<<1, 1024, 0, stream>>>(image, boff, sidx, anyv, imgt, eiP, eiM);
    k_gbuckets<<<Hn / 2, 256, 0, stream>>>(W1, boff, sidx, G_T);
    k_w1bulk<<<2048, 256, 0, stream>>>(W1, o_W1);
    k_c1M<<<Hn / 32, 256, 0, stream>>>(G_T, M, r1pre, o_r1);
    k_sel<<<Tt, 256, 0, stream>>>(M, cand);
    k_fused<<<1 + NB_W2 + NB_W3T, 512, 0, stream>>>(
        M, cand, thr1, W2, W3, o_W2, W3T, r1pre, o_r1, j1s, mh, nRout);
    k_lif2<<<Nn / 64, 64, 0, stream>>>(W2, j1s, thr2, o_r2, spkb, anyv);
    k_sim3<<<1, 128, 0, stream>>>(spkb, anyv, W3T, thr3, o_r3);
    k_post<<<1 + 256 + 128, 256, 0, stream>>>(image, r1pre, o_r1, o_r2, o_r3,
        imgt, eiP, eiM, W1, W3, mh, nRout, zeta, rho, Pv, Qv, o_err, o_es, o_W1, o_W3);
    k_w2fix<<<Nn, 128, 0, stream>>>(o_r1, Pv, Qv, o_r2, rho, mh, nRout, o_W2);
}

// Round 17
// 523.462 us; speedup vs baseline: 1.0712x; 1.0712x over previous
//
#include <hip/hip_runtime.h>
#include <cstdint>
#include <cstddef>

#define Hn 8192
#define Nn 4096
#define Cn 128
#define Tt 256
#define CAP 192

typedef unsigned long long ull;

// th after nup clip-updates (decay -0.05 each) from base b, clamped [lo,hi]
__device__ __forceinline__ float th_lazy2(float b, float lo, float hi, int nup){
    if (nup <= 0) return b;
    float a = fminf(fmaxf(__fsub_rn(b, 0.05f), lo), hi);
    if (nup == 1) return a;
    return fmaxf(__fsub_rn(a, __fmul_rn(0.05f, (float)(nup - 1))), lo);
}

__device__ __forceinline__ float clamp01(float v){
    return fminf(fmaxf(v, 0.f), 1.f);
}

// ---- DPP cross-lane reduce (VALU pipe) ----
template<int CTRL>
__device__ __forceinline__ int dpp_i(int x, int old){
    return __builtin_amdgcn_update_dpp(old, x, CTRL, 0xf, 0xf, false);
}
__device__ __forceinline__ float wave_max_f(float v){
    const int NEG = __float_as_int(-3.4e38f);
#define STEPM(C) { float o = __int_as_float(dpp_i<C>(__float_as_int(v), NEG)); v = fmaxf(v, o); }
    STEPM(0x111) STEPM(0x112) STEPM(0x114) STEPM(0x118) STEPM(0x142) STEPM(0x143)
#undef STEPM
    return __int_as_float(__builtin_amdgcn_readlane(__float_as_int(v), 63));
}
// argmax (value desc, index asc); returns winner lane, sets wv/wh.
__device__ __forceinline__ int wave_argmax_l(float bv, int bh, float &wv, int &wh){
    float v = wave_max_f(bv);
    ull tie = __ballot(bv == v);
    int tl = __ffsll((long long)tie) - 1;
    int h = __builtin_amdgcn_readlane(bh, tl);
    if (__builtin_expect(__popcll(tie) > 1, 0)){
        ull m = tie & (tie - 1);
        while (m){
            int l2 = __ffsll((long long)m) - 1;
            int h2 = __builtin_amdgcn_readlane(bh, l2);
            if (h2 < h){ h = h2; tl = l2; }
            m &= m - 1;
        }
    }
    wv = v; wh = h; return tl;
}
__device__ __forceinline__ float rl_f(float x, int l){
    return __int_as_float(__builtin_amdgcn_readlane(__float_as_int(x), l));
}

// ---------------- k_prep: buckets + counting sort + image exp tables ----------------
__global__ __launch_bounds__(1024) void k_prep(const float* __restrict__ image,
        int* __restrict__ boff, int* __restrict__ sidx, unsigned* __restrict__ anyv,
        float* __restrict__ imgt, float* __restrict__ eiP, float* __restrict__ eiM){
    __shared__ int s_start[Nn];
    __shared__ int s_c4[4][Tt];
    __shared__ int s_boff[Tt + 1];
    int tid = threadIdx.x;
    for (int i = tid; i < Nn; i += 1024){
        float im = image[i];
        float img = __fmul_rn(256.f, im);
        s_start[i] = (int)floorf(img);
        imgt[i] = img;
        eiP[i] = __expf(img * 0.05f);
        eiM[i] = __expf(-img * 0.05f);
    }
    if (tid < Tt) anyv[tid] = 0u;
    __syncthreads();
    int b = tid & 255, q = tid >> 8;
    {
        int c = 0;
        for (int k = 0; k < 1024; ++k) c += (s_start[q * 1024 + k] == b) ? 1 : 0;
        s_c4[q][b] = c;
    }
    __syncthreads();
    if (tid == 0){
        int acc = 0;
        for (int bb = 0; bb < Tt; ++bb){
            s_boff[bb] = acc;
            acc += s_c4[0][bb] + s_c4[1][bb] + s_c4[2][bb] + s_c4[3][bb];
        }
        s_boff[Tt] = acc;
    }
    __syncthreads();
    if (tid <= Tt) boff[tid] = s_boff[tid];
    int p = s_boff[b];
    if (q > 0) p += s_c4[0][b];
    if (q > 1) p += s_c4[1][b];
    if (q > 2) p += s_c4[2][b];
    for (int k = 0; k < 1024; ++k){
        int i = q * 1024 + k;
        if (s_start[i] == b) sidx[p++] = i;
    }
}

// ---------------- k_gbuckets: 2 rows/block, 32 KB LDS ----------------
__global__ __launch_bounds__(256) void k_gbuckets(const float* __restrict__ W1,
        const int* __restrict__ boff, const int* __restrict__ sidx,
        float* __restrict__ G_T){
    __shared__ float rows[2][Nn];
    int tid = threadIdx.x;
    int h0 = blockIdx.x * 2;
    for (int r = 0; r < 2; ++r){
        const float4* src = (const float4*)(W1 + (size_t)(h0 + r) * Nn);
        float4* dst = (float4*)rows[r];
        for (int j = tid; j < Nn / 4; j += 256) dst[j] = src[j];
    }
    __syncthreads();
    int t = tid;
    int b0 = boff[t], b1 = boff[t + 1];
    float s0 = 0.f, s1 = 0.f;
    for (int k = b0; k < b1; ++k){
        int i = sidx[k];
        s0 += rows[0][i]; s1 += rows[1][i];
    }
    G_T[(size_t)(h0 + 0) * Tt + t] = s0;
    G_T[(size_t)(h0 + 1) * Tt + t] = s1;
}

// ---------------- k_c1M: window-sum + M-scan + r1 init ----------------
__global__ __launch_bounds__(256) void k_c1M(const float* __restrict__ G_T,
        float* __restrict__ M, float* __restrict__ r1pre, float* __restrict__ o_r1){
    __shared__ float tile[32][Tt + 1];
    __shared__ float c1s[32][Tt + 1];
    const int tid = threadIdx.x;
    const int h0 = blockIdx.x * 32;
    for (int r = 0; r < 32; ++r) tile[r][tid] = G_T[(size_t)(h0 + r) * Tt + tid];
    __syncthreads();
    {
        int hs = tid & 31, ts = tid >> 5;
        for (int tb = 0; tb < 32; ++tb){
            int t = tb * 8 + ts;
            int lo = (t - 7 < 0) ? 0 : t - 7;
            float s = 0.f;
            for (int u = lo; u <= t; ++u) s += tile[hs][u];
            c1s[hs][t] = s;
        }
    }
    __syncthreads();
    if (tid < 32){
        float m = 0.f;
        for (int t = 0; t < Tt; ++t){
            m = __fadd_rn(__fmul_rn(0.9f, m), c1s[tid][t]);
            M[(size_t)t * Hn + h0 + tid] = m;
        }
        r1pre[h0 + tid] = 0.f;
        o_r1[h0 + tid] = 256.f;
    }
}

// ---------------- k_sel: rank-CAP radix select; cand = (val, idx|valid<<15, 0, vcap) ----------------
__global__ __launch_bounds__(256) void k_sel(const float* __restrict__ M,
        float4* __restrict__ cand){
    const int t = blockIdx.x, tid = threadIdx.x;
    __shared__ float s_row[Hn];
    __shared__ unsigned s_hist[256];
    __shared__ unsigned s_suf[256];
    __shared__ unsigned s_pref;
    __shared__ int s_rank;
    __shared__ int s_cnt;
    __shared__ int s_idx[CAP + 64];
    {
        const float4* src = (const float4*)(M + (size_t)t * Hn);
        float4* d4 = (float4*)s_row;
        for (int j = tid; j < Hn / 4; j += 256) d4[j] = src[j];
    }
    if (tid == 0){ s_pref = 0u; s_rank = CAP; s_cnt = 0; }
    __syncthreads();
#pragma unroll
    for (int b = 3; b >= 0; --b){
        s_hist[tid] = 0u;
        __syncthreads();
        unsigned pref = s_pref;
        int r = s_rank;
        for (int k = 0; k < 32; ++k){
            unsigned u = __float_as_uint(s_row[tid + (k << 8)]);
            bool match = (b == 3) ? true : ((u >> ((b + 1) * 8)) == pref);
            if (match) atomicAdd(&s_hist[(u >> (b * 8)) & 255], 1u);
        }
        __syncthreads();
        s_suf[tid] = s_hist[tid];
        __syncthreads();
#pragma unroll
        for (int off = 1; off < 256; off <<= 1){
            unsigned v = (tid + off < 256) ? s_suf[tid + off] : 0u;
            __syncthreads();
            s_suf[tid] += v;
            __syncthreads();
        }
        unsigned above = s_suf[tid] - s_hist[tid];
        if ((int)above < r && r <= (int)s_suf[tid]){
            s_pref = (pref << 8) | (unsigned)tid;
            s_rank = r - (int)above;
        }
        __syncthreads();
    }
    unsigned V = s_pref;
    for (int k = 0; k < 32; ++k){
        int i = tid + (k << 8);
        unsigned u = __float_as_uint(s_row[i]);
        if (u >= V){
            int p = atomicAdd(&s_cnt, 1);
            if (p < CAP + 64) s_idx[p] = i;
        }
    }
    __syncthreads();
    int c = s_cnt;
    bool ovf = (c > CAP);
    float vV = ovf ? 3.4e38f : __uint_as_float(V);
    for (int i = tid; i < CAP; i += 256){
        float4 e;
        if (!ovf && i < c){
            int ix = s_idx[i];
            e = make_float4(s_row[ix], __int_as_float(ix | (1 << 15)), 0.f, vV);
        } else {
            e = make_float4(-1.f, 0.f, 0.f, vV);
        }
        cand[(size_t)t * CAP + i] = e;
    }
}

// ---------------- k_fused: block0 = WTA + postmap (1024 thr); blocks 1.. = W1/W2 bulk + W3T ----------------
#define NB_W1 1024
#define NB_W2 1024
#define NB_W3T 128

union FusedLDS {
    struct {
        float4 mst[Hn];             // 128 KB (off, ts, thb, 0)
        int j1[Tt];                 // 1 KB
        unsigned bm[256];           // 1 KB
    } w;
    float tl[64][65];               // W3T tile
};

__global__ __launch_bounds__(1024, 1) void k_fused(
        const float* __restrict__ M, const float4* __restrict__ cand,
        const float* __restrict__ thr1,
        const float* __restrict__ W1, const float* __restrict__ W2,
        const float* __restrict__ W3,
        float* __restrict__ o_W1, float* __restrict__ o_W2, float* __restrict__ W3T,
        float* __restrict__ r1pre, float* __restrict__ o_r1,
        int* __restrict__ j1s, int* __restrict__ mh, int* __restrict__ nRout){
    __shared__ FusedLDS u;
    const int bid = blockIdx.x;
    const int tid = threadIdx.x;

    if (bid >= 1 && bid < 1 + NB_W1){
        // W1 bulk (L3-resident read): 16 waves/CU streaming
        size_t base = (size_t)(bid - 1) * 8192;
        const float4* src = (const float4*)W1;
        float4* dst = (float4*)o_W1;
        for (int i = tid; i < 8192; i += 4096){
            float4 a0 = src[base + i];
            float4 a1 = src[base + i + 1024];
            float4 a2 = src[base + i + 2048];
            float4 a3 = src[base + i + 3072];
            a0.x = __fadd_rn(a0.x, 0.01f); a0.y = __fadd_rn(a0.y, 0.01f);
            a0.z = __fadd_rn(a0.z, 0.01f); a0.w = __fadd_rn(a0.w, 0.01f);
            a1.x = __fadd_rn(a1.x, 0.01f); a1.y = __fadd_rn(a1.y, 0.01f);
            a1.z = __fadd_rn(a1.z, 0.01f); a1.w = __fadd_rn(a1.w, 0.01f);
            a2.x = __fadd_rn(a2.x, 0.01f); a2.y = __fadd_rn(a2.y, 0.01f);
            a2.z = __fadd_rn(a2.z, 0.01f); a2.w = __fadd_rn(a2.w, 0.01f);
            a3.x = __fadd_rn(a3.x, 0.01f); a3.y = __fadd_rn(a3.y, 0.01f);
            a3.z = __fadd_rn(a3.z, 0.01f); a3.w = __fadd_rn(a3.w, 0.01f);
            dst[base + i]        = a0;
            dst[base + i + 1024] = a1;
            dst[base + i + 2048] = a2;
            dst[base + i + 3072] = a3;
        }
        return;
    }
    if (bid >= 1 + NB_W1 && bid < 1 + NB_W1 + NB_W2){
        size_t base = (size_t)(bid - 1 - NB_W1) * 8192;
        const float4* src = (const float4*)W2;
        float4* dst = (float4*)o_W2;
        for (int i = tid; i < 8192; i += 4096){
            float4 a0 = src[base + i];
            float4 a1 = src[base + i + 1024];
            float4 a2 = src[base + i + 2048];
            float4 a3 = src[base + i + 3072];
            a0.x = clamp01(a0.x); a0.y = clamp01(a0.y); a0.z = clamp01(a0.z); a0.w = clamp01(a0.w);
            a1.x = clamp01(a1.x); a1.y = clamp01(a1.y); a1.z = clamp01(a1.z); a1.w = clamp01(a1.w);
            a2.x = clamp01(a2.x); a2.y = clamp01(a2.y); a2.z = clamp01(a2.z); a2.w = clamp01(a2.w);
            a3.x = clamp01(a3.x); a3.y = clamp01(a3.y); a3.z = clamp01(a3.z); a3.w = clamp01(a3.w);
            dst[base + i]        = a0;
            dst[base + i + 1024] = a1;
            dst[base + i + 2048] = a2;
            dst[base + i + 3072] = a3;
        }
        return;
    }
    if (bid >= 1 + NB_W1 + NB_W2){
        int r = bid - 1 - NB_W1 - NB_W2;
        int bx = r & 63, by = r >> 6;
        int n0 = bx * 64, c0 = by * 64;
        for (int e = tid; e < 64 * 64; e += 1024){
            int rr = e >> 6, cc = e & 63;
            u.tl[rr][cc] = W3[(size_t)(c0 + rr) * Nn + n0 + cc];
        }
        __syncthreads();
        for (int e = tid; e < 64 * 64; e += 1024){
            int rn = e >> 6, cc = e & 63;
            W3T[(size_t)(n0 + rn) * Cn + c0 + cc] = u.tl[cc][rn];
        }
        return;
    }

    // ---- block 0: init state table, then single-wave WTA ----
    for (int h = tid; h < Hn; h += 1024)
        u.w.mst[h] = make_float4(0.f, -1.f, thr1[h], 0.f);
    __syncthreads();
    if (tid >= 64) return;
    const int lane = tid;
    const float Lc = -0.15200309344504997f;   // log2(0.9)

    float4 cA0 = cand[lane],         cA1 = cand[64 + lane],         cA2 = cand[128 + lane];
    float4 cB0 = cand[CAP + lane],   cB1 = cand[CAP + 64 + lane],   cB2 = cand[CAP + 128 + lane];
    float4 cC0 = cand[2*CAP + lane], cC1 = cand[2*CAP + 64 + lane], cC2 = cand[2*CAP + 128 + lane];
    float4 gA0, gA1, gA2;
    {
        int h0 = __float_as_int(cA0.y) & 8191;
        int h1 = __float_as_int(cA1.y) & 8191;
        int h2 = __float_as_int(cA2.y) & 8191;
        gA0 = u.w.mst[h0]; gA1 = u.w.mst[h1]; gA2 = u.w.mst[h2];
    }

    for (int t = 0; t < Tt; ++t){
        const float tf = (float)t;
        float bm = -3.4e38f; int bhh = 0x7FFFFFFF;
        float braw = 0.f, bts = 0.f, bthb = 0.f;
#define CPROC(c) { \
        int mc = __float_as_int(cA##c.y); \
        int hc = mc & 8191; \
        float dd = __fsub_rn(tf, gA##c.y); \
        float mem = __fsub_rn(cA##c.x, __fmul_rn(exp2f(__fmul_rn(dd, Lc)), gA##c.x)); \
        if (!((mc >> 15) & 1)) mem = -3.4e38f; \
        if (mem > bm || (mem == bm && hc < bhh)){ bm = mem; bhh = hc; braw = cA##c.x; bts = gA##c.y; bthb = gA##c.z; } }
        CPROC(0) CPROC(1) CPROC(2)
#undef CPROC
        const int hB0 = __float_as_int(cB0.y) & 8191;
        const int hB1 = __float_as_int(cB1.y) & 8191;
        const int hB2 = __float_as_int(cB2.y) & 8191;
        float4 gB0 = u.w.mst[hB0];
        float4 gB1 = u.w.mst[hB1];
        float4 gB2 = u.w.mst[hB2];
        float wv; int wh;
        int wl = wave_argmax_l(bm, bhh, wv, wh);
        float raw = rl_f(braw, wl), tsv = rl_f(bts, wl), thb = rl_f(bthb, wl);
        const float vc = cA0.w;
        int skip = 0;
        if (__builtin_expect(wv < vc, 0)){
            if (t > 0 && vc < 150.f){
                skip = 1;
            } else {
                float fv = -3.4e38f; int fh = 0x7FFFFFFF;
                float fraw = 0.f, fts = 0.f, fthb = 0.f;
                const float4* Mrow4 = (const float4*)(M + (size_t)t * Hn);
                for (int q = 0; q < 32; ++q){
                    int e = q * 64 + lane;
                    float4 mv = Mrow4[e];
                    int ib = e * 4;
                    float4 g0 = u.w.mst[ib+0], g1 = u.w.mst[ib+1], g2 = u.w.mst[ib+2], g3 = u.w.mst[ib+3];
#define FPROC(comp, gg, o2) { float x = mv.comp; float dd = __fsub_rn(tf, gg.y); \
                    float mm = __fsub_rn(x, __fmul_rn(exp2f(__fmul_rn(dd, Lc)), gg.x)); \
                    int h2 = ib + o2; \
                    if (mm > fv || (mm == fv && h2 < fh)){ fv = mm; fh = h2; fraw = x; fts = gg.y; fthb = gg.z; } }
                    FPROC(x, g0, 0) FPROC(y, g1, 1) FPROC(z, g2, 2) FPROC(w, g3, 3)
#undef FPROC
                }
                wl = wave_argmax_l(fv, fh, wv, wh);
                raw = rl_f(fraw, wl); tsv = rl_f(fts, wl); thb = rl_f(fthb, wl);
            }
        }
        int fire = 0; float thnew = 0.f;
        if (!skip){
            float te = th_lazy2(thb, 150.f, 400.f, t - (int)tsv - 1);
            if (wv > te){
                fire = 1;
                thnew = fminf(fmaxf(__fadd_rn(__fsub_rn(te, 0.05f), 5.0f), 150.f), 400.f);
            }
        }
        if (fire){
            if (lane == 0){
                u.w.j1[t] = wh;
                if (tsv < 0.f){ o_r1[wh] = tf + 1.f; r1pre[wh] = tf + 1.f; }
                u.w.mst[wh] = make_float4(raw, tf, thnew, 0.f);
            }
            float4 upd = make_float4(raw, tf, thnew, 0.f);
            if (hB0 == wh) gB0 = upd;
            if (hB1 == wh) gB1 = upd;
            if (hB2 == wh) gB2 = upd;
        } else {
            if (lane == 0) u.w.j1[t] = -1;
        }
        cA0 = cB0; cA1 = cB1; cA2 = cB2;
        cB0 = cC0; cB1 = cC1; cB2 = cC2;
        int tn = (t + 3 < Tt) ? t + 3 : Tt - 1;
        cC0 = cand[(size_t)tn * CAP + lane];
        cC1 = cand[(size_t)tn * CAP + 64 + lane];
        cC2 = cand[(size_t)tn * CAP + 128 + lane];
        gA0 = gB0; gA1 = gB1; gA2 = gB2;
    }

    // ---- single-wave postmap ----
    for (int i = lane; i < 256; i += 64) u.w.bm[i] = 0u;
    asm volatile("s_waitcnt lgkmcnt(0)" ::: "memory");
    for (int i = lane; i < Tt; i += 64){
        int h = u.w.j1[i];
        j1s[i] = h;
        if (h >= 0) atomicOr(&u.w.bm[h >> 5], 1u << (h & 31));
    }
    asm volatile("s_waitcnt lgkmcnt(0)" ::: "memory");
    unsigned w0 = u.w.bm[lane*4+0], w1 = u.w.bm[lane*4+1];
    unsigned w2 = u.w.bm[lane*4+2], w3 = u.w.bm[lane*4+3];
    int c = __popc(w0) + __popc(w1) + __popc(w2) + __popc(w3);
    int inc = c;
#pragma unroll
    for (int off = 1; off < 64; off <<= 1){
        int v = __shfl_up(inc, off);
        if (lane >= off) inc += v;
    }
    int b = inc - c;
#define WALK(wrd, k) { unsigned ww = wrd; while (ww){ int bt = __ffs(ww) - 1; ww &= ww - 1; \
        mh[b++] = ((lane * 4 + k) << 5) | bt; } }
    WALK(w0, 0) WALK(w1, 1) WALK(w2, 2) WALK(w3, 3)
#undef WALK
    if (lane == 63) *nRout = inc;
}

// ---------------- k_lif2: direct-W2 LIF, depth-4 named-reg prefetch ----------------
__global__ __launch_bounds__(64) void k_lif2(const float* __restrict__ W2,
        const int* __restrict__ j1s, const float* __restrict__ thr2,
        float* __restrict__ o_r2, ull* __restrict__ spkb, unsigned* __restrict__ anyv){
    __shared__ int s_j[Tt];
    int lane = threadIdx.x, blk = blockIdx.x;
    for (int i = lane; i < Tt; i += 64) s_j[i] = j1s[i];
    __syncthreads();
    int n = blk * 64 + lane;
    const float* Wrow = W2 + (size_t)n * Hn;
    float tv = thr2[n], m = 0.f, rp = 0.f;
#define LD(dst, tt) { int hh = s_j[tt]; dst = (hh >= 0) ? Wrow[hh] : 0.f; }
#define STEP(uu, tt) { m = __fadd_rn(__fmul_rn(0.8f, m), uu); int f = 0; \
        if (m > tv){ m = __fsub_rn(m, tv); if (rp == 0.f) rp = (float)((tt) + 1); f = 1; } \
        ull mask = __ballot(f); \
        if (lane == 0){ spkb[(tt) * 64 + blk] = mask; if (mask) atomicOr(&anyv[tt], 1u); } }
    float u0, u1, u2, u3;
    LD(u0, 0) LD(u1, 1) LD(u2, 2) LD(u3, 3)
    for (int g = 0; g < 64; ++g){
        float v0 = 0.f, v1 = 0.f, v2 = 0.f, v3 = 0.f;
        if (g < 63){
            int bb = (g + 1) * 4;
            LD(v0, bb) LD(v1, bb + 1) LD(v2, bb + 2) LD(v3, bb + 3)
        }
        int t = g * 4;
        STEP(u0, t) STEP(u1, t + 1) STEP(u2, t + 2) STEP(u3, t + 3)
        u0 = v0; u1 = v1; u2 = v2; u3 = v3;
    }
#undef LD
#undef STEP
    o_r2[n] = (rp == 0.f) ? 256.f : rp;
}

// ---------------- k_sim3: spkb preloaded to LDS (128 KB) ----------------
__global__ __launch_bounds__(128, 1) void k_sim3(const ull* __restrict__ spkb,
        const unsigned* __restrict__ anyv, const float* __restrict__ W3T,
        const float* __restrict__ thr3, float* __restrict__ o_r3){
    int tid = threadIdx.x, lane = tid & 63, w = tid >> 6;
    __shared__ ull s_spk[Tt * 64];     // 128 KB
    __shared__ unsigned s_any[Tt];
    __shared__ ull s_r2[2];
    __shared__ int s_fire;
    {
        const uint4* src = (const uint4*)spkb;
        uint4* dst = (uint4*)s_spk;
        for (int i = tid; i < Tt * 64 / 2; i += 128) dst[i] = src[i];
    }
    for (int i = tid; i < Tt; i += 128) s_any[i] = anyv[i];
    float m = 0.f, th0 = thr3[tid], rp = 0.f, thv = 0.f;
    int ts = -1, zero = 1;
    __syncthreads();
    for (int t = 0; t < Tt; ++t){
        if (zero && s_any[t] == 0u) continue;
        float d = 0.f;
        if (s_any[t]){
            for (int ww = 0; ww < 64; ++ww){
                ull bits = s_spk[t * 64 + ww];
                while (bits){
                    int b2 = __ffsll((long long)bits) - 1;
                    bits &= bits - 1;
                    d = __fadd_rn(d, W3T[(size_t)(ww * 64 + b2) * Cn + tid]);
                }
            }
        }
        m = __fadd_rn(__fmul_rn(0.9f, m), d);
        ull k = (((ull)__float_as_uint(m >= 0.f ? m : 0.f)) << 32) | (unsigned)(8191 - tid);
        if (!(m >= 0.f)) k = (unsigned)(8191 - tid);
#pragma unroll
        for (int off = 32; off >= 1; off >>= 1){
            ull o = __shfl_down(k, off);
            if (o > k) k = o;
        }
        if (lane == 0) s_r2[w] = k;
        __syncthreads();
        ull wk = s_r2[0] > s_r2[1] ? s_r2[0] : s_r2[1];
        int wc = 8191 - (int)(wk & 0xFFFFu);
        float wv = __uint_as_float((unsigned)(wk >> 32));
        if (tid == wc){
            float te = (ts < 0) ? th_lazy2(th0, 50.f, 200.f, t)
                                : th_lazy2(thv, 50.f, 200.f, t - ts - 1);
            int f = (wv > te) ? 1 : 0;
            s_fire = f;
            if (f){
                thv = fminf(fmaxf(__fadd_rn(__fsub_rn(te, 0.05f), 5.0f), 50.f), 200.f);
                ts = t;
                if (rp == 0.f) rp = (float)(t + 1);
            }
        }
        __syncthreads();
        if (s_fire){ m = 0.f; zero = 1; }
        else zero = 0;
        __syncthreads();
    }
    o_r3[tid] = (rp == 0.f) ? 256.f : rp;
}

// ---------------- k_post: block0 = scalars; 1..256 = w1fix; 257..384 = w3new ----------------
__global__ __launch_bounds__(256) void k_post(const float* __restrict__ image,
        const float* __restrict__ r1pre, const float* __restrict__ o_r1,
        const float* __restrict__ o_r2, const float* __restrict__ o_r3,
        const float* __restrict__ imgt, const float* __restrict__ eiP,
        const float* __restrict__ eiM,
        const float* __restrict__ W1, const float* __restrict__ W3,
        const int* __restrict__ mh, const int* __restrict__ nRout,
        float* __restrict__ zeta, float* __restrict__ rho,
        float* __restrict__ Pv, float* __restrict__ Qv,
        float* __restrict__ o_err, float* __restrict__ o_es,
        float* __restrict__ o_W1, float* __restrict__ o_W3){
    const int bid = blockIdx.x;
    const int tid = threadIdx.x;
    if (bid == 0){
        for (int h = tid; h < Hn; h += 256){
            float r1f = o_r1[h];
            float mask = (r1pre[h] != 0.f) ? 1.f : 0.f;
            float z = __fmul_rn(__fmul_rn(__fsub_rn(256.f, r1f), mask), 0.00390625f);
            zeta[h] = z;
            Pv[h] = __expf(r1f * 0.05f) * z;
            Qv[h] = __expf(-r1f * 0.05f) * z;
        }
        float acc = 0.f;
        for (int n = tid; n < Nn; n += 256){
            float img = __fmul_rn(256.f, image[n]);
            float r2f = o_r2[n];
            float e = __fmul_rn(__fsub_rn(img, __fsub_rn(r2f, 4.0f)), 0.00390625f);
            o_err[n] = e;
            rho[n] = __fadd_rn(__fmul_rn(__fsub_rn(__fsub_rn(r2f, 4.0f), img), 0.00390625f), 0.15f);
            acc = __fadd_rn(acc, __fmul_rn(e, e));
        }
        __shared__ float red[4];
        for (int off = 32; off >= 1; off >>= 1) acc += __shfl_down(acc, off);
        int lane = tid & 63, w = tid >> 6;
        if (lane == 0) red[w] = acc;
        __syncthreads();
        if (tid == 0) *o_es = red[0] + red[1] + red[2] + red[3];
        return;
    }
    if (bid <= 256){
        int slot = bid - 1;
        if (slot >= *nRout) return;
        int h = mh[slot];
        float r1f = o_r1[h];
        float a = 0.01f * __expf(-r1f * 0.05f);
        float b = 0.01f * __expf( r1f * 0.05f);
        const float4* src = (const float4*)(W1 + (size_t)h * Nn);
        float4* dst = (float4*)(o_W1 + (size_t)h * Nn);
        const float4* ig = (const float4*)imgt;
        const float4* p4 = (const float4*)eiP;
        const float4* m4 = (const float4*)eiM;
        for (int i = tid; i < Nn / 4; i += 256){
            float4 s = src[i];
            float4 im = ig[i], pp = p4[i], mm = m4[i];
            s.x += (r1f >= im.x) ? a * pp.x : -(b * mm.x);
            s.y += (r1f >= im.y) ? a * pp.y : -(b * mm.y);
            s.z += (r1f >= im.z) ? a * pp.z : -(b * mm.z);
            s.w += (r1f >= im.w) ? a * pp.w : -(b * mm.w);
            dst[i] = s;
        }
        return;
    }
    {
        int cc = bid - 257;
        float r3f = o_r3[cc];
        float a = 0.01f * __expf(-r3f * 0.05f);
        float b = 0.01f * __expf( r3f * 0.05f);
        const float4* src = (const float4*)(W3 + (size_t)cc * Nn);
        float4* dst = (float4*)(o_W3 + (size_t)cc * Nn);
        const float4* r24 = (const float4*)o_r2;
        for (int i = tid; i < Nn / 4; i += 256){
            float4 s = src[i]; float4 rv = r24[i];
            s.x += (r3f >= rv.x) ? a * __expf(rv.x * 0.05f) : -(b * __expf(-rv.x * 0.05f));
            s.y += (r3f >= rv.y) ? a * __expf(rv.y * 0.05f) : -(b * __expf(-rv.y * 0.05f));
            s.z += (r3f >= rv.z) ? a * __expf(rv.z * 0.05f) : -(b * __expf(-rv.z * 0.05f));
            s.w += (r3f >= rv.w) ? a * __expf(rv.w * 0.05f) : -(b * __expf(-rv.w * 0.05f));
            dst[i] = s;
        }
    }
}

// ---------------- k_w2fix ----------------
__global__ __launch_bounds__(128) void k_w2fix(
        const float* __restrict__ o_r1, const float* __restrict__ Pv,
        const float* __restrict__ Qv, const float* __restrict__ o_r2,
        const float* __restrict__ rho, const int* __restrict__ mh,
        const int* __restrict__ nRout, float* __restrict__ o_W2){
    __shared__ int   s_h[Tt];
    __shared__ float s_rv[Tt], s_pp[Tt], s_qq[Tt];
    int n = blockIdx.x, tid = threadIdx.x;
    int nRv = *nRout;
    for (int s = tid; s < nRv; s += 128){
        int h = mh[s];
        s_h[s] = h; s_rv[s] = o_r1[h]; s_pp[s] = Pv[h]; s_qq[s] = Qv[h];
    }
    __syncthreads();
    float r2f = o_r2[n], rh = rho[n];
    float A = 0.01f * rh * __expf(-r2f * 0.05f);
    float B = 0.01f * rh * __expf( r2f * 0.05f);
    for (int s = tid; s < nRv; s += 128){
        size_t idx = (size_t)n * Hn + s_h[s];
        float w = o_W2[idx];
        float rv = s_rv[s];
        w = clamp01(w + ((r2f >= rv) ? A * s_pp[s] : -(B * s_qq[s])));
        o_W2[idx] = w;
    }
}

extern "C" void kernel_launch(void* const* d_in, const int* in_sizes, int n_in,
                              void* d_out, int out_size, void* d_ws, size_t ws_size,
                              hipStream_t stream){
    const float* image = (const float*)d_in[0];
    const float* W1   = (const float*)d_in[1];
    const float* W2   = (const float*)d_in[2];
    const float* W3   = (const float*)d_in[3];
    const float* thr1 = (const float*)d_in[4];
    const float* thr2 = (const float*)d_in[5];
    const float* thr3 = (const float*)d_in[6];

    float* out  = (float*)d_out;
    float* o_err = out;
    float* o_es  = out + 4096;
    float* o_r1  = out + 4097;
    float* o_r2  = out + 12289;
    float* o_r3  = out + 16385;
    float* o_W1  = out + 16513;
    float* o_W2  = o_W1 + (size_t)Hn * Nn;
    float* o_W3  = o_W2 + (size_t)Nn * Hn;

    float* ws = (float*)d_ws;
    float* G_T   = ws;                                  // H*T
    float* M     = G_T + (size_t)Hn * Tt;               // T*H
    float* W3T   = M + (size_t)Tt * Hn;                 // N*C
    float4* cand = (float4*)(W3T + (size_t)Nn * Cn);    // T*CAP float4
    ull* spkb    = (ull*)(cand + (size_t)Tt * CAP);     // T*64
    float* r1pre = (float*)(spkb + (size_t)Tt * 64);    // H
    float* zeta  = r1pre + Hn;                          // H
    float* rho   = zeta + Hn;                           // N
    float* imgt  = rho + Nn;                            // N
    float* eiP   = imgt + Nn;                           // N
    float* eiM   = eiP + Nn;                            // N
    float* Pv    = eiM + Nn;                            // H
    float* Qv    = Pv + Hn;                             // H
    int* boff   = (int*)(Qv + Hn);                      // T+1
    int* sidx   = boff + (Tt + 1);                      // N
    int* j1s    = sidx + Nn;                            // T (h-indices)
    int* mh     = j1s + Tt;                             // 256
    int* nRout  = mh + 256;                             // 1
    unsigned* anyv = (unsigned*)(nRout + 1);            // T

    k_prep<<<1, 1024, 0, stream>>>(image, boff, sidx, anyv, imgt, eiP, eiM);
    k_gbuckets<<<Hn / 2, 256, 0, stream>>>(W1, boff, sidx, G_T);
    k_c1M<<<Hn / 32, 256, 0, stream>>>(G_T, M, r1pre, o_r1);
    k_sel<<<Tt, 256, 0, stream>>>(M, cand);
    k_fused<<<1 + NB_W1 + NB_W2 + NB_W3T, 1024, 0, stream>>>(
        M, cand, thr1, W1, W2, W3, o_W1, o_W2, W3T, r1pre, o_r1, j1s, mh, nRout);
    k_lif2<<<Nn / 64, 64, 0, stream>>>(W2, j1s, thr2, o_r2, spkb, anyv);
    k_sim3<<<1, 128, 0, stream>>>(spkb, anyv, W3T, thr3, o_r3);
    k_post<<<1 + 256 + 128, 256, 0, stream>>>(image, r1pre, o_r1, o_r2, o_r3,
        imgt, eiP, eiM, W1, W3, mh, nRout, zeta, rho, Pv, Qv, o_err, o_es, o_W1, o_W3);
    k_w2fix<<<Nn, 128, 0, stream>>>(o_r1, Pv, Qv, o_r2, rho, mh, nRout, o_W2);
}

// Round 18
// 504.035 us; speedup vs baseline: 1.1125x; 1.0385x over previous
//
#include <hip/hip_runtime.h>
#include <cstdint>
#include <cstddef>

#define Hn 8192
#define Nn 4096
#define Cn 128
#define Tt 256
#define CAP 192
#define CHUNK 8
#define RING 16

typedef unsigned long long ull;

// th after nup clip-updates (decay -0.05 each) from base b, clamped [lo,hi]
__device__ __forceinline__ float th_lazy2(float b, float lo, float hi, int nup){
    if (nup <= 0) return b;
    float a = fminf(fmaxf(__fsub_rn(b, 0.05f), lo), hi);
    if (nup == 1) return a;
    return fmaxf(__fsub_rn(a, __fmul_rn(0.05f, (float)(nup - 1))), lo);
}

__device__ __forceinline__ float clamp01(float v){
    return fminf(fmaxf(v, 0.f), 1.f);
}

// ---- DPP cross-lane reduce (VALU pipe) ----
template<int CTRL>
__device__ __forceinline__ int dpp_i(int x, int old){
    return __builtin_amdgcn_update_dpp(old, x, CTRL, 0xf, 0xf, false);
}
__device__ __forceinline__ float wave_max_f(float v){
    const int NEG = __float_as_int(-3.4e38f);
#define STEPM(C) { float o = __int_as_float(dpp_i<C>(__float_as_int(v), NEG)); v = fmaxf(v, o); }
    STEPM(0x111) STEPM(0x112) STEPM(0x114) STEPM(0x118) STEPM(0x142) STEPM(0x143)
#undef STEPM
    return __int_as_float(__builtin_amdgcn_readlane(__float_as_int(v), 63));
}
// argmax (value desc, index asc); returns winner lane, sets wv/wh.
__device__ __forceinline__ int wave_argmax_l(float bv, int bh, float &wv, int &wh){
    float v = wave_max_f(bv);
    ull tie = __ballot(bv == v);
    int tl = __ffsll((long long)tie) - 1;
    int h = __builtin_amdgcn_readlane(bh, tl);
    if (__builtin_expect(__popcll(tie) > 1, 0)){
        ull m = tie & (tie - 1);
        while (m){
            int l2 = __ffsll((long long)m) - 1;
            int h2 = __builtin_amdgcn_readlane(bh, l2);
            if (h2 < h){ h = h2; tl = l2; }
            m &= m - 1;
        }
    }
    wv = v; wh = h; return tl;
}
__device__ __forceinline__ float rl_f(float x, int l){
    return __int_as_float(__builtin_amdgcn_readlane(__float_as_int(x), l));
}

// ---------------- k_prep: buckets + counting sort + image exp tables ----------------
__global__ __launch_bounds__(1024) void k_prep(const float* __restrict__ image,
        int* __restrict__ boff, int* __restrict__ sidx, unsigned* __restrict__ anyv,
        float* __restrict__ imgt, float* __restrict__ eiP, float* __restrict__ eiM){
    __shared__ int s_start[Nn];
    __shared__ int s_c4[4][Tt];
    __shared__ int s_boff[Tt + 1];
    int tid = threadIdx.x;
    for (int i = tid; i < Nn; i += 1024){
        float im = image[i];
        float img = __fmul_rn(256.f, im);
        s_start[i] = (int)floorf(img);
        imgt[i] = img;
        eiP[i] = __expf(img * 0.05f);
        eiM[i] = __expf(-img * 0.05f);
    }
    if (tid < Tt) anyv[tid] = 0u;
    __syncthreads();
    int b = tid & 255, q = tid >> 8;
    {
        int c = 0;
        for (int k = 0; k < 1024; ++k) c += (s_start[q * 1024 + k] == b) ? 1 : 0;
        s_c4[q][b] = c;
    }
    __syncthreads();
    if (tid == 0){
        int acc = 0;
        for (int bb = 0; bb < Tt; ++bb){
            s_boff[bb] = acc;
            acc += s_c4[0][bb] + s_c4[1][bb] + s_c4[2][bb] + s_c4[3][bb];
        }
        s_boff[Tt] = acc;
    }
    __syncthreads();
    if (tid <= Tt) boff[tid] = s_boff[tid];
    int p = s_boff[b];
    if (q > 0) p += s_c4[0][b];
    if (q > 1) p += s_c4[1][b];
    if (q > 2) p += s_c4[2][b];
    for (int k = 0; k < 1024; ++k){
        int i = q * 1024 + k;
        if (s_start[i] == b) sidx[p++] = i;
    }
}

// ---------------- k_gbuckets: 2 rows/block + fused o_W1 = W1 + 0.01 write ----------------
__global__ __launch_bounds__(256) void k_gbuckets(const float* __restrict__ W1,
        const int* __restrict__ boff, const int* __restrict__ sidx,
        float* __restrict__ G_T, float* __restrict__ o_W1){
    __shared__ float rows[2][Nn];
    int tid = threadIdx.x;
    int h0 = blockIdx.x * 2;
    for (int r = 0; r < 2; ++r){
        const float4* src = (const float4*)(W1 + (size_t)(h0 + r) * Nn);
        float4* dst = (float4*)rows[r];
        for (int j = tid; j < Nn / 4; j += 256) dst[j] = src[j];
    }
    __syncthreads();
    int t = tid;
    int b0 = boff[t], b1 = boff[t + 1];
    float s0 = 0.f, s1 = 0.f;
    for (int k = b0; k < b1; ++k){
        int i = sidx[k];
        s0 += rows[0][i]; s1 += rows[1][i];
    }
    G_T[(size_t)(h0 + 0) * Tt + t] = s0;
    G_T[(size_t)(h0 + 1) * Tt + t] = s1;
    // fused W1 bulk: o_W1 = W1 + 0.01 (reuses LDS-staged rows)
    for (int r = 0; r < 2; ++r){
        const float4* srw = (const float4*)rows[r];
        float4* dw = (float4*)(o_W1 + (size_t)(h0 + r) * Nn);
        for (int j = tid; j < Nn / 4; j += 256){
            float4 s = srw[j];
            s.x = __fadd_rn(s.x, 0.01f); s.y = __fadd_rn(s.y, 0.01f);
            s.z = __fadd_rn(s.z, 0.01f); s.w = __fadd_rn(s.w, 0.01f);
            dw[j] = s;
        }
    }
}

// ---------------- k_c1M: window-sum + M-scan + r1 init ----------------
__global__ __launch_bounds__(256) void k_c1M(const float* __restrict__ G_T,
        float* __restrict__ M, float* __restrict__ r1pre, float* __restrict__ o_r1){
    __shared__ float tile[32][Tt + 1];
    __shared__ float c1s[32][Tt + 1];
    const int tid = threadIdx.x;
    const int h0 = blockIdx.x * 32;
    for (int r = 0; r < 32; ++r) tile[r][tid] = G_T[(size_t)(h0 + r) * Tt + tid];
    __syncthreads();
    {
        int hs = tid & 31, ts = tid >> 5;
        for (int tb = 0; tb < 32; ++tb){
            int t = tb * 8 + ts;
            int lo = (t - 7 < 0) ? 0 : t - 7;
            float s = 0.f;
            for (int u = lo; u <= t; ++u) s += tile[hs][u];
            c1s[hs][t] = s;
        }
    }
    __syncthreads();
    if (tid < 32){
        float m = 0.f;
        for (int t = 0; t < Tt; ++t){
            m = __fadd_rn(__fmul_rn(0.9f, m), c1s[tid][t]);
            M[(size_t)t * Hn + h0 + tid] = m;
        }
        r1pre[h0 + tid] = 0.f;
        o_r1[h0 + tid] = 256.f;
    }
}

// ---------------- k_sel: rank-CAP radix select; cand2 = (val, idx|valid<<15); gvcap ----------------
__global__ __launch_bounds__(256) void k_sel(const float* __restrict__ M,
        float2* __restrict__ cand2, float* __restrict__ gvcap){
    const int t = blockIdx.x, tid = threadIdx.x;
    __shared__ float s_row[Hn];
    __shared__ unsigned s_hist[256];
    __shared__ unsigned s_suf[256];
    __shared__ unsigned s_pref;
    __shared__ int s_rank;
    __shared__ int s_cnt;
    __shared__ int s_idx[CAP + 64];
    {
        const float4* src = (const float4*)(M + (size_t)t * Hn);
        float4* d4 = (float4*)s_row;
        for (int j = tid; j < Hn / 4; j += 256) d4[j] = src[j];
    }
    if (tid == 0){ s_pref = 0u; s_rank = CAP; s_cnt = 0; }
    __syncthreads();
#pragma unroll
    for (int b = 3; b >= 0; --b){
        s_hist[tid] = 0u;
        __syncthreads();
        unsigned pref = s_pref;
        int r = s_rank;
        for (int k = 0; k < 32; ++k){
            unsigned u = __float_as_uint(s_row[tid + (k << 8)]);
            bool match = (b == 3) ? true : ((u >> ((b + 1) * 8)) == pref);
            if (match) atomicAdd(&s_hist[(u >> (b * 8)) & 255], 1u);
        }
        __syncthreads();
        s_suf[tid] = s_hist[tid];
        __syncthreads();
#pragma unroll
        for (int off = 1; off < 256; off <<= 1){
            unsigned v = (tid + off < 256) ? s_suf[tid + off] : 0u;
            __syncthreads();
            s_suf[tid] += v;
            __syncthreads();
        }
        unsigned above = s_suf[tid] - s_hist[tid];
        if ((int)above < r && r <= (int)s_suf[tid]){
            s_pref = (pref << 8) | (unsigned)tid;
            s_rank = r - (int)above;
        }
        __syncthreads();
    }
    unsigned V = s_pref;
    for (int k = 0; k < 32; ++k){
        int i = tid + (k << 8);
        unsigned u = __float_as_uint(s_row[i]);
        if (u >= V){
            int p = atomicAdd(&s_cnt, 1);
            if (p < CAP + 64) s_idx[p] = i;
        }
    }
    __syncthreads();
    int c = s_cnt;
    bool ovf = (c > CAP);
    if (tid == 0) gvcap[t] = ovf ? 3.4e38f : __uint_as_float(V);
    for (int i = tid; i < CAP; i += 256){
        float2 e;
        if (!ovf && i < c){
            int ix = s_idx[i];
            e = make_float2(s_row[ix], __int_as_float(ix | (1 << 15)));
        } else {
            e = make_float2(-1.f, 0.f);
        }
        cand2[(size_t)t * CAP + i] = e;
    }
}

// ---------------- k_fused: block0 = ring-fed WTA + postmap; blocks 1.. = W2 bulk + W3T ----------------
#define NB_W2 1024
#define NB_W3T 128

union FusedLDS {
    struct {
        float4 mst[Hn];             // 128 KB (off, ts, thb, 0)
        float2 ring[RING][CAP];     // 24 KB candidate ring
        float  vcr[RING];           // 64 B
        int j1[Tt];                 // 1 KB
        unsigned bm[256];           // 1 KB
    } w;
    float tl[64][65];               // W3T tile
};

__global__ __launch_bounds__(1024, 1) void k_fused(
        const float* __restrict__ M, const float2* __restrict__ cand2,
        const float* __restrict__ gvcap, const float* __restrict__ thr1,
        const float* __restrict__ W2, const float* __restrict__ W3,
        float* __restrict__ o_W2, float* __restrict__ W3T,
        float* __restrict__ r1pre, float* __restrict__ o_r1,
        int* __restrict__ j1s, int* __restrict__ mh, int* __restrict__ nRout){
    __shared__ FusedLDS u;
    const int bid = blockIdx.x;
    const int tid = threadIdx.x;

    if (bid >= 1 && bid < 1 + NB_W2){
        size_t base = (size_t)(bid - 1) * 8192;
        const float4* src = (const float4*)W2;
        float4* dst = (float4*)o_W2;
        for (int i = tid; i < 8192; i += 4096){
            float4 a0 = src[base + i];
            float4 a1 = src[base + i + 1024];
            float4 a2 = src[base + i + 2048];
            float4 a3 = src[base + i + 3072];
            a0.x = clamp01(a0.x); a0.y = clamp01(a0.y); a0.z = clamp01(a0.z); a0.w = clamp01(a0.w);
            a1.x = clamp01(a1.x); a1.y = clamp01(a1.y); a1.z = clamp01(a1.z); a1.w = clamp01(a1.w);
            a2.x = clamp01(a2.x); a2.y = clamp01(a2.y); a2.z = clamp01(a2.z); a2.w = clamp01(a2.w);
            a3.x = clamp01(a3.x); a3.y = clamp01(a3.y); a3.z = clamp01(a3.z); a3.w = clamp01(a3.w);
            dst[base + i]        = a0;
            dst[base + i + 1024] = a1;
            dst[base + i + 2048] = a2;
            dst[base + i + 3072] = a3;
        }
        return;
    }
    if (bid >= 1 + NB_W2){
        int r = bid - 1 - NB_W2;
        int bx = r & 63, by = r >> 6;
        int n0 = bx * 64, c0 = by * 64;
        for (int e = tid; e < 64 * 64; e += 1024){
            int rr = e >> 6, cc = e & 63;
            u.tl[rr][cc] = W3[(size_t)(c0 + rr) * Nn + n0 + cc];
        }
        __syncthreads();
        for (int e = tid; e < 64 * 64; e += 1024){
            int rn = e >> 6, cc = e & 63;
            W3T[(size_t)(n0 + rn) * Cn + c0 + cc] = u.tl[cc][rn];
        }
        return;
    }

    // ---- block 0: init state + chunk-0 ring, then ring-fed single-wave WTA ----
    for (int h = tid; h < Hn; h += 1024)
        u.w.mst[h] = make_float4(0.f, -1.f, thr1[h], 0.f);
    for (int e = tid; e < CHUNK * CAP; e += 1024){
        int so = e / CAP, j = e - so * CAP;
        u.w.ring[so][j] = cand2[(size_t)so * CAP + j];
    }
    if (tid < CHUNK) u.w.vcr[tid] = gvcap[tid];
    __syncthreads();

    const int lane = tid & 63;
    const float Lc = -0.15200309344504997f;   // log2(0.9)

    for (int c = 0; c < Tt / CHUNK; ++c){
        if (tid >= 64 && c + 1 < Tt / CHUNK){
            // producers: load chunk c+1 into ring
            for (int e = tid - 64; e < CHUNK * CAP; e += 960){
                int so = e / CAP, j = e - so * CAP;
                int step = (c + 1) * CHUNK + so;
                u.w.ring[step & (RING - 1)][j] = cand2[(size_t)step * CAP + j];
            }
            if (tid - 64 < CHUNK){
                int step = (c + 1) * CHUNK + (tid - 64);
                u.w.vcr[step & (RING - 1)] = gvcap[step];
            }
        }
        if (tid < 64){
            for (int s = 0; s < CHUNK; ++s){
                const int t = c * CHUNK + s;
                const int slot = t & (RING - 1);
                const float tf = (float)t;
                // candidate + state reads (same-wave DS order => always current)
                float2 e0 = u.w.ring[slot][lane];
                float2 e1 = u.w.ring[slot][64 + lane];
                float2 e2 = u.w.ring[slot][128 + lane];
                float vc = u.w.vcr[slot];
                int m0b = __float_as_int(e0.y), m1b = __float_as_int(e1.y), m2b = __float_as_int(e2.y);
                int h0 = m0b & 8191, h1 = m1b & 8191, h2 = m2b & 8191;
                float4 g0 = u.w.mst[h0];
                float4 g1 = u.w.mst[h1];
                float4 g2 = u.w.mst[h2];
                float bm = -3.4e38f; int bhh = 0x7FFFFFFF;
                float braw = 0.f, bts = 0.f, bthb = 0.f;
#define CPROC(ee, mb, hh, gg) { \
                float dd = __fsub_rn(tf, gg.y); \
                float mem = __fsub_rn(ee.x, __fmul_rn(exp2f(__fmul_rn(dd, Lc)), gg.x)); \
                if (!((mb >> 15) & 1)) mem = -3.4e38f; \
                if (mem > bm || (mem == bm && hh < bhh)){ bm = mem; bhh = hh; braw = ee.x; bts = gg.y; bthb = gg.z; } }
                CPROC(e0, m0b, h0, g0) CPROC(e1, m1b, h1, g1) CPROC(e2, m2b, h2, g2)
#undef CPROC
                float wv; int wh;
                int wl = wave_argmax_l(bm, bhh, wv, wh);
                float raw = rl_f(braw, wl), tsv = rl_f(bts, wl), thb = rl_f(bthb, wl);
                int skip = 0;
                if (__builtin_expect(wv < vc, 0)){
                    if (t > 0 && vc < 150.f){
                        skip = 1;
                    } else {
                        float fv = -3.4e38f; int fh = 0x7FFFFFFF;
                        float fraw = 0.f, fts = 0.f, fthb = 0.f;
                        const float4* Mrow4 = (const float4*)(M + (size_t)t * Hn);
                        for (int q = 0; q < 32; ++q){
                            int e = q * 64 + lane;
                            float4 mv = Mrow4[e];
                            int ib = e * 4;
                            float4 q0 = u.w.mst[ib+0], q1 = u.w.mst[ib+1], q2 = u.w.mst[ib+2], q3 = u.w.mst[ib+3];
#define FPROC(comp, gg, o2) { float x = mv.comp; float dd = __fsub_rn(tf, gg.y); \
                            float mm = __fsub_rn(x, __fmul_rn(exp2f(__fmul_rn(dd, Lc)), gg.x)); \
                            int hh2 = ib + o2; \
                            if (mm > fv || (mm == fv && hh2 < fh)){ fv = mm; fh = hh2; fraw = x; fts = gg.y; fthb = gg.z; } }
                            FPROC(x, q0, 0) FPROC(y, q1, 1) FPROC(z, q2, 2) FPROC(w, q3, 3)
#undef FPROC
                        }
                        wl = wave_argmax_l(fv, fh, wv, wh);
                        raw = rl_f(fraw, wl); tsv = rl_f(fts, wl); fthb = rl_f(fthb, wl); thb = fthb;
                    }
                }
                int fire = 0; float thnew = 0.f;
                if (!skip){
                    float te = th_lazy2(thb, 150.f, 400.f, t - (int)tsv - 1);
                    if (wv > te){
                        fire = 1;
                        thnew = fminf(fmaxf(__fadd_rn(__fsub_rn(te, 0.05f), 5.0f), 150.f), 400.f);
                    }
                }
                if (fire){
                    if (lane == 0){
                        u.w.j1[t] = wh;
                        if (tsv < 0.f){ o_r1[wh] = tf + 1.f; r1pre[wh] = tf + 1.f; }
                        u.w.mst[wh] = make_float4(raw, tf, thnew, 0.f);
                    }
                } else {
                    if (lane == 0) u.w.j1[t] = -1;
                }
            }
        }
        __syncthreads();
    }
    if (tid >= 64) return;

    // ---- single-wave postmap ----
    for (int i = lane; i < 256; i += 64) u.w.bm[i] = 0u;
    asm volatile("s_waitcnt lgkmcnt(0)" ::: "memory");
    for (int i = lane; i < Tt; i += 64){
        int h = u.w.j1[i];
        j1s[i] = h;
        if (h >= 0) atomicOr(&u.w.bm[h >> 5], 1u << (h & 31));
    }
    asm volatile("s_waitcnt lgkmcnt(0)" ::: "memory");
    unsigned w0 = u.w.bm[lane*4+0], w1 = u.w.bm[lane*4+1];
    unsigned w2 = u.w.bm[lane*4+2], w3 = u.w.bm[lane*4+3];
    int c = __popc(w0) + __popc(w1) + __popc(w2) + __popc(w3);
    int inc = c;
#pragma unroll
    for (int off = 1; off < 64; off <<= 1){
        int v = __shfl_up(inc, off);
        if (lane >= off) inc += v;
    }
    int b = inc - c;
#define WALK(wrd, k) { unsigned ww = wrd; while (ww){ int bt = __ffs(ww) - 1; ww &= ww - 1; \
        mh[b++] = ((lane * 4 + k) << 5) | bt; } }
    WALK(w0, 0) WALK(w1, 1) WALK(w2, 2) WALK(w3, 3)
#undef WALK
    if (lane == 63) *nRout = inc;
}

// ---------------- k_lif2: direct-W2 LIF, depth-4 named-reg prefetch ----------------
__global__ __launch_bounds__(64) void k_lif2(const float* __restrict__ W2,
        const int* __restrict__ j1s, const float* __restrict__ thr2,
        float* __restrict__ o_r2, ull* __restrict__ spkb, unsigned* __restrict__ anyv){
    __shared__ int s_j[Tt];
    int lane = threadIdx.x, blk = blockIdx.x;
    for (int i = lane; i < Tt; i += 64) s_j[i] = j1s[i];
    __syncthreads();
    int n = blk * 64 + lane;
    const float* Wrow = W2 + (size_t)n * Hn;
    float tv = thr2[n], m = 0.f, rp = 0.f;
#define LD(dst, tt) { int hh = s_j[tt]; dst = (hh >= 0) ? Wrow[hh] : 0.f; }
#define STEP(uu, tt) { m = __fadd_rn(__fmul_rn(0.8f, m), uu); int f = 0; \
        if (m > tv){ m = __fsub_rn(m, tv); if (rp == 0.f) rp = (float)((tt) + 1); f = 1; } \
        ull mask = __ballot(f); \
        if (lane == 0){ spkb[(tt) * 64 + blk] = mask; if (mask) atomicOr(&anyv[tt], 1u); } }
    float u0, u1, u2, u3;
    LD(u0, 0) LD(u1, 1) LD(u2, 2) LD(u3, 3)
    for (int g = 0; g < 64; ++g){
        float v0 = 0.f, v1 = 0.f, v2 = 0.f, v3 = 0.f;
        if (g < 63){
            int bb = (g + 1) * 4;
            LD(v0, bb) LD(v1, bb + 1) LD(v2, bb + 2) LD(v3, bb + 3)
        }
        int t = g * 4;
        STEP(u0, t) STEP(u1, t + 1) STEP(u2, t + 2) STEP(u3, t + 3)
        u0 = v0; u1 = v1; u2 = v2; u3 = v3;
    }
#undef LD
#undef STEP
    o_r2[n] = (rp == 0.f) ? 256.f : rp;
}

// ---------------- k_sim3: spkb preloaded to LDS (128 KB) ----------------
__global__ __launch_bounds__(128, 1) void k_sim3(const ull* __restrict__ spkb,
        const unsigned* __restrict__ anyv, const float* __restrict__ W3T,
        const float* __restrict__ thr3, float* __restrict__ o_r3){
    int tid = threadIdx.x, lane = tid & 63, w = tid >> 6;
    __shared__ ull s_spk[Tt * 64];     // 128 KB
    __shared__ unsigned s_any[Tt];
    __shared__ ull s_r2[2];
    __shared__ int s_fire;
    {
        const uint4* src = (const uint4*)spkb;
        uint4* dst = (uint4*)s_spk;
        for (int i = tid; i < Tt * 64 / 2; i += 128) dst[i] = src[i];
    }
    for (int i = tid; i < Tt; i += 128) s_any[i] = anyv[i];
    float m = 0.f, th0 = thr3[tid], rp = 0.f, thv = 0.f;
    int ts = -1, zero = 1;
    __syncthreads();
    for (int t = 0; t < Tt; ++t){
        if (zero && s_any[t] == 0u) continue;
        float d = 0.f;
        if (s_any[t]){
            for (int ww = 0; ww < 64; ++ww){
                ull bits = s_spk[t * 64 + ww];
                while (bits){
                    int b2 = __ffsll((long long)bits) - 1;
                    bits &= bits - 1;
                    d = __fadd_rn(d, W3T[(size_t)(ww * 64 + b2) * Cn + tid]);
                }
            }
        }
        m = __fadd_rn(__fmul_rn(0.9f, m), d);
        ull k = (((ull)__float_as_uint(m >= 0.f ? m : 0.f)) << 32) | (unsigned)(8191 - tid);
        if (!(m >= 0.f)) k = (unsigned)(8191 - tid);
#pragma unroll
        for (int off = 32; off >= 1; off >>= 1){
            ull o = __shfl_down(k, off);
            if (o > k) k = o;
        }
        if (lane == 0) s_r2[w] = k;
        __syncthreads();
        ull wk = s_r2[0] > s_r2[1] ? s_r2[0] : s_r2[1];
        int wc = 8191 - (int)(wk & 0xFFFFu);
        float wv = __uint_as_float((unsigned)(wk >> 32));
        if (tid == wc){
            float te = (ts < 0) ? th_lazy2(th0, 50.f, 200.f, t)
                                : th_lazy2(thv, 50.f, 200.f, t - ts - 1);
            int f = (wv > te) ? 1 : 0;
            s_fire = f;
            if (f){
                thv = fminf(fmaxf(__fadd_rn(__fsub_rn(te, 0.05f), 5.0f), 50.f), 200.f);
                ts = t;
                if (rp == 0.f) rp = (float)(t + 1);
            }
        }
        __syncthreads();
        if (s_fire){ m = 0.f; zero = 1; }
        else zero = 0;
        __syncthreads();
    }
    o_r3[tid] = (rp == 0.f) ? 256.f : rp;
}

// ---------------- k_post: block0 = scalars; 1..256 = w1fix; 257..384 = w3new ----------------
__global__ __launch_bounds__(256) void k_post(const float* __restrict__ image,
        const float* __restrict__ r1pre, const float* __restrict__ o_r1,
        const float* __restrict__ o_r2, const float* __restrict__ o_r3,
        const float* __restrict__ imgt, const float* __restrict__ eiP,
        const float* __restrict__ eiM,
        const float* __restrict__ W1, const float* __restrict__ W3,
        const int* __restrict__ mh, const int* __restrict__ nRout,
        float* __restrict__ zeta, float* __restrict__ rho,
        float* __restrict__ Pv, float* __restrict__ Qv,
        float* __restrict__ o_err, float* __restrict__ o_es,
        float* __restrict__ o_W1, float* __restrict__ o_W3){
    const int bid = blockIdx.x;
    const int tid = threadIdx.x;
    if (bid == 0){
        for (int h = tid; h < Hn; h += 256){
            float r1f = o_r1[h];
            float mask = (r1pre[h] != 0.f) ? 1.f : 0.f;
            float z = __fmul_rn(__fmul_rn(__fsub_rn(256.f, r1f), mask), 0.00390625f);
            zeta[h] = z;
            Pv[h] = __expf(r1f * 0.05f) * z;
            Qv[h] = __expf(-r1f * 0.05f) * z;
        }
        float acc = 0.f;
        for (int n = tid; n < Nn; n += 256){
            float img = __fmul_rn(256.f, image[n]);
            float r2f = o_r2[n];
            float e = __fmul_rn(__fsub_rn(img, __fsub_rn(r2f, 4.0f)), 0.00390625f);
            o_err[n] = e;
            rho[n] = __fadd_rn(__fmul_rn(__fsub_rn(__fsub_rn(r2f, 4.0f), img), 0.00390625f), 0.15f);
            acc = __fadd_rn(acc, __fmul_rn(e, e));
        }
        __shared__ float red[4];
        for (int off = 32; off >= 1; off >>= 1) acc += __shfl_down(acc, off);
        int lane = tid & 63, w = tid >> 6;
        if (lane == 0) red[w] = acc;
        __syncthreads();
        if (tid == 0) *o_es = red[0] + red[1] + red[2] + red[3];
        return;
    }
    if (bid <= 256){
        int slot = bid - 1;
        if (slot >= *nRout) return;
        int h = mh[slot];
        float r1f = o_r1[h];
        float a = 0.01f * __expf(-r1f * 0.05f);
        float b = 0.01f * __expf( r1f * 0.05f);
        const float4* src = (const float4*)(W1 + (size_t)h * Nn);
        float4* dst = (float4*)(o_W1 + (size_t)h * Nn);
        const float4* ig = (const float4*)imgt;
        const float4* p4 = (const float4*)eiP;
        const float4* m4 = (const float4*)eiM;
        for (int i = tid; i < Nn / 4; i += 256){
            float4 s = src[i];
            float4 im = ig[i], pp = p4[i], mm = m4[i];
            s.x += (r1f >= im.x) ? a * pp.x : -(b * mm.x);
            s.y += (r1f >= im.y) ? a * pp.y : -(b * mm.y);
            s.z += (r1f >= im.z) ? a * pp.z : -(b * mm.z);
            s.w += (r1f >= im.w) ? a * pp.w : -(b * mm.w);
            dst[i] = s;
        }
        return;
    }
    {
        int cc = bid - 257;
        float r3f = o_r3[cc];
        float a = 0.01f * __expf(-r3f * 0.05f);
        float b = 0.01f * __expf( r3f * 0.05f);
        const float4* src = (const float4*)(W3 + (size_t)cc * Nn);
        float4* dst = (float4*)(o_W3 + (size_t)cc * Nn);
        const float4* r24 = (const float4*)o_r2;
        for (int i = tid; i < Nn / 4; i += 256){
            float4 s = src[i]; float4 rv = r24[i];
            s.x += (r3f >= rv.x) ? a * __expf(rv.x * 0.05f) : -(b * __expf(-rv.x * 0.05f));
            s.y += (r3f >= rv.y) ? a * __expf(rv.y * 0.05f) : -(b * __expf(-rv.y * 0.05f));
            s.z += (r3f >= rv.z) ? a * __expf(rv.z * 0.05f) : -(b * __expf(-rv.z * 0.05f));
            s.w += (r3f >= rv.w) ? a * __expf(rv.w * 0.05f) : -(b * __expf(-rv.w * 0.05f));
            dst[i] = s;
        }
    }
}

// ---------------- k_w2fix ----------------
__global__ __launch_bounds__(128) void k_w2fix(
        const float* __restrict__ o_r1, const float* __restrict__ Pv,
        const float* __restrict__ Qv, const float* __restrict__ o_r2,
        const float* __restrict__ rho, const int* __restrict__ mh,
        const int* __restrict__ nRout, float* __restrict__ o_W2){
    __shared__ int   s_h[Tt];
    __shared__ float s_rv[Tt], s_pp[Tt], s_qq[Tt];
    int n = blockIdx.x, tid = threadIdx.x;
    int nRv = *nRout;
    for (int s = tid; s < nRv; s += 128){
        int h = mh[s];
        s_h[s] = h; s_rv[s] = o_r1[h]; s_pp[s] = Pv[h]; s_qq[s] = Qv[h];
    }
    __syncthreads();
    float r2f = o_r2[n], rh = rho[n];
    float A = 0.01f * rh * __expf(-r2f * 0.05f);
    float B = 0.01f * rh * __expf( r2f * 0.05f);
    for (int s = tid; s < nRv; s += 128){
        size_t idx = (size_t)n * Hn + s_h[s];
        float w = o_W2[idx];
        float rv = s_rv[s];
        w = clamp01(w + ((r2f >= rv) ? A * s_pp[s] : -(B * s_qq[s])));
        o_W2[idx] = w;
    }
}

extern "C" void kernel_launch(void* const* d_in, const int* in_sizes, int n_in,
                              void* d_out, int out_size, void* d_ws, size_t ws_size,
                              hipStream_t stream){
    const float* image = (const float*)d_in[0];
    const float* W1   = (const float*)d_in[1];
    const float* W2   = (const float*)d_in[2];
    const float* W3   = (const float*)d_in[3];
    const float* thr1 = (const float*)d_in[4];
    const float* thr2 = (const float*)d_in[5];
    const float* thr3 = (const float*)d_in[6];

    float* out  = (float*)d_out;
    float* o_err = out;
    float* o_es  = out + 4096;
    float* o_r1  = out + 4097;
    float* o_r2  = out + 12289;
    float* o_r3  = out + 16385;
    float* o_W1  = out + 16513;
    float* o_W2  = o_W1 + (size_t)Hn * Nn;
    float* o_W3  = o_W2 + (size_t)Nn * Hn;

    float* ws = (float*)d_ws;
    float* G_T   = ws;                                  // H*T
    float* M     = G_T + (size_t)Hn * Tt;               // T*H
    float* W3T   = M + (size_t)Tt * Hn;                 // N*C
    float2* cand2 = (float2*)(W3T + (size_t)Nn * Cn);   // T*CAP float2
    float* gvcap = (float*)(cand2 + (size_t)Tt * CAP);  // T
    ull* spkb    = (ull*)(gvcap + Tt);                  // T*64
    float* r1pre = (float*)(spkb + (size_t)Tt * 64);    // H
    float* zeta  = r1pre + Hn;                          // H
    float* rho   = zeta + Hn;                           // N
    float* imgt  = rho + Nn;                            // N
    float* eiP   = imgt + Nn;                           // N
    float* eiM   = eiP + Nn;                            // N
    float* Pv    = eiM + Nn;                            // H
    float* Qv    = Pv + Hn;                             // H
    int* boff   = (int*)(Qv + Hn);                      // T+1
    int* sidx   = boff + (Tt + 1);                      // N
    int* j1s    = sidx + Nn;                            // T (h-indices)
    int* mh     = j1s + Tt;                             // 256
    int* nRout  = mh + 256;                             // 1
    unsigned* anyv = (unsigned*)(nRout + 1);            // T

    k_prep<<<1, 1024, 0, stream>>>(image, boff, sidx, anyv, imgt, eiP, eiM);
    k_gbuckets<<<Hn / 2, 256, 0, stream>>>(W1, boff, sidx, G_T, o_W1);
    k_c1M<<<Hn / 32, 256, 0, stream>>>(G_T, M, r1pre, o_r1);
    k_sel<<<Tt, 256, 0, stream>>>(M, cand2, gvcap);
    k_fused<<<1 + NB_W2 + NB_W3T, 1024, 0, stream>>>(
        M, cand2, gvcap, thr1, W2, W3, o_W2, W3T, r1pre, o_r1, j1s, mh, nRout);
    k_lif2<<<Nn / 64, 64, 0, stream>>>(W2, j1s, thr2, o_r2, spkb, anyv);
    k_sim3<<<1, 128, 0, stream>>>(spkb, anyv, W3T, thr3, o_r3);
    k_post<<<1 + 256 + 128, 256, 0, stream>>>(image, r1pre, o_r1, o_r2, o_r3,
        imgt, eiP, eiM, W1, W3, mh, nRout, zeta, rho, Pv, Qv, o_err, o_es, o_W1, o_W3);
    k_w2fix<<<Nn, 128, 0, stream>>>(o_r1, Pv, Qv, o_r2, rho, mh, nRout, o_W2);
}